// Round 2
// baseline (7308.933 us; speedup 1.0000x reference)
//
#include <hip/hip_runtime.h>
#include <hip/hip_bf16.h>

#define EPS 1e-5f

// ---------------------------------------------------------------------------
// Stage 1: x [8,1,100,7500]; chunks n in [n0, n0+G) of the 120 = 8*15.
// fused conv5x5(pad2, 1->16) + BN + ReLU + maxpool2x2 -> out [G,16,50,250]
// ---------------------------------------------------------------------------
__global__ __launch_bounds__(256) void conv1_kernel(
    const float* __restrict__ x,
    const float* __restrict__ w, const float* __restrict__ bias,
    const float* __restrict__ g, const float* __restrict__ beta,
    const float* __restrict__ m, const float* __restrict__ v,
    float* __restrict__ out, int n0)
{
    const int nl = blockIdx.z;                 // local chunk index in group
    const int n  = n0 + nl;                    // global 0..119  (b*15 + chunk)
    const int co = blockIdx.y;                 // 0..15
    const int sp = blockIdx.x * 256 + threadIdx.x;
    if (sp >= 50 * 250) return;
    const int ph = sp / 250, pw = sp % 250;
    const int b = n / 15, c = n % 15;
    const float* xb = x + (size_t)b * 100 * 7500 + (size_t)c * 500;

    float wk[25];
    #pragma unroll
    for (int i = 0; i < 25; ++i) wk[i] = w[co * 25 + i];

    const int y0 = 2 * ph - 2, x0 = 2 * pw - 2;
    float win[6][6];
    #pragma unroll
    for (int r = 0; r < 6; ++r) {
        const int y = y0 + r;
        const bool yv = (y >= 0 && y < 100);
        #pragma unroll
        for (int cc = 0; cc < 6; ++cc) {
            const int xx = x0 + cc;
            win[r][cc] = (yv && xx >= 0 && xx < 500) ? xb[y * 7500 + xx] : 0.f;
        }
    }
    float a00 = 0.f, a01 = 0.f, a10 = 0.f, a11 = 0.f;
    #pragma unroll
    for (int kh = 0; kh < 5; ++kh)
        #pragma unroll
        for (int kw = 0; kw < 5; ++kw) {
            const float wv = wk[kh * 5 + kw];
            a00 += win[kh][kw] * wv;     a01 += win[kh][kw + 1] * wv;
            a10 += win[kh + 1][kw] * wv; a11 += win[kh + 1][kw + 1] * wv;
        }
    const float sc = g[co] / sqrtf(v[co] + EPS);
    const float sh = (bias[co] - m[co]) * sc + beta[co];
    a00 = fmaxf(a00 * sc + sh, 0.f); a01 = fmaxf(a01 * sc + sh, 0.f);
    a10 = fmaxf(a10 * sc + sh, 0.f); a11 = fmaxf(a11 * sc + sh, 0.f);
    out[(((size_t)nl * 16 + co) * 50 + ph) * 250 + pw] =
        fmaxf(fmaxf(a00, a01), fmaxf(a10, a11));
}

// ---------------------------------------------------------------------------
// Stages 2-4: generic fused conv5x5(pad2)+BN+ReLU+maxpool2x2(VALID)
// in [G,CI,H,W] -> out [G,CO,PH,PW]   (PH=floor(H/2), PW=floor(W/2))
// ---------------------------------------------------------------------------
template <int CI, int CO, int H, int W, int PH, int PW>
__global__ __launch_bounds__(256) void convblk_kernel(
    const float* __restrict__ in,
    const float* __restrict__ w, const float* __restrict__ bias,
    const float* __restrict__ g, const float* __restrict__ beta,
    const float* __restrict__ m, const float* __restrict__ v,
    float* __restrict__ out)
{
    __shared__ float wlds[CI * 25];
    const int n = blockIdx.z, co = blockIdx.y;
    for (int i = threadIdx.x; i < CI * 25; i += 256) wlds[i] = w[co * CI * 25 + i];
    __syncthreads();

    const int sp = blockIdx.x * 256 + threadIdx.x;
    if (sp >= PH * PW) return;
    const int ph = sp / PW, pw = sp % PW;
    const int y0 = 2 * ph - 2, x0 = 2 * pw - 2;
    const float* inb = in + (size_t)n * CI * H * W;

    float a00 = 0.f, a01 = 0.f, a10 = 0.f, a11 = 0.f;
    for (int ci = 0; ci < CI; ++ci) {
        const float* inc = inb + (size_t)ci * H * W;
        float win[6][6];
        #pragma unroll
        for (int r = 0; r < 6; ++r) {
            const int y = y0 + r;
            const bool yv = (y >= 0 && y < H);
            #pragma unroll
            for (int cc = 0; cc < 6; ++cc) {
                const int xx = x0 + cc;
                win[r][cc] = (yv && xx >= 0 && xx < W) ? inc[y * W + xx] : 0.f;
            }
        }
        const float* wc = &wlds[ci * 25];
        #pragma unroll
        for (int kh = 0; kh < 5; ++kh)
            #pragma unroll
            for (int kw = 0; kw < 5; ++kw) {
                const float wv = wc[kh * 5 + kw];
                a00 += win[kh][kw] * wv;     a01 += win[kh][kw + 1] * wv;
                a10 += win[kh + 1][kw] * wv; a11 += win[kh + 1][kw + 1] * wv;
            }
    }
    const float sc = g[co] / sqrtf(v[co] + EPS);
    const float sh = (bias[co] - m[co]) * sc + beta[co];
    a00 = fmaxf(a00 * sc + sh, 0.f); a01 = fmaxf(a01 * sc + sh, 0.f);
    a10 = fmaxf(a10 * sc + sh, 0.f); a11 = fmaxf(a11 * sc + sh, 0.f);
    out[(((size_t)n * CO + co) * PH + ph) * PW + pw] =
        fmaxf(fmaxf(a00, a01), fmaxf(a10, a11));
}

// ---------------------------------------------------------------------------
// FC: feats [G,5952] @ wfc[32,5952]^T + bfc -> res[(n0+nl)*32 + o] (global)
// one block per local n; 4 waves; each wave does 8 outputs, shuffle-reduced
// ---------------------------------------------------------------------------
__global__ __launch_bounds__(256) void fc_kernel(
    const float* __restrict__ feats, const float* __restrict__ wfc,
    const float* __restrict__ bfc, float* __restrict__ res, int n0)
{
    const int nl = blockIdx.x;
    const int lane = threadIdx.x & 63;
    const int wave = threadIdx.x >> 6;
    const float* f = feats + (size_t)nl * 5952;
    for (int o8 = 0; o8 < 8; ++o8) {
        const int o = wave * 8 + o8;
        const float* wr = wfc + (size_t)o * 5952;
        float s = 0.f;
        for (int k = lane; k < 5952; k += 64) s += f[k] * wr[k];
        #pragma unroll
        for (int off = 32; off > 0; off >>= 1) s += __shfl_down(s, off, 64);
        if (lane == 0) res[(n0 + nl) * 32 + o] = s + bfc[o];
    }
}

// ---------------------------------------------------------------------------
// DPCNN head, entirely in one block. res [120,32] -> out [8,2]
// r[b][c][h]: b=8 batches, c=15 channels, h=32 -> pyramid 32->16->8->4->2
// ---------------------------------------------------------------------------
__global__ __launch_bounds__(256) void dpcnn_kernel(
    const float* __restrict__ res,
    const float* __restrict__ wc3, const float* __restrict__ bc3,
    const float* __restrict__ wout, const float* __restrict__ bout,
    float* __restrict__ out)
{
    __shared__ float r[8][15][32];
    __shared__ float t[8][15][32];
    __shared__ float px[8][15][16];
    __shared__ float wk[15][15][3];
    __shared__ float bk[15];

    const int tid = threadIdx.x;
    for (int i = tid; i < 15 * 15 * 3; i += 256) ((float*)wk)[i] = wc3[i];
    if (tid < 15) bk[tid] = bc3[tid];
    for (int i = tid; i < 8 * 15 * 32; i += 256) {
        // res flat index == b*480 + c*32 + h which is exactly i
        const int h = i & 31, c = (i >> 5) % 15, b = i / 480;
        r[b][c][h] = res[i];
    }
    __syncthreads();

    // two full-height conv3(relu(pad)) passes at H=32
    for (int pass = 0; pass < 2; ++pass) {
        for (int i = tid; i < 8 * 15 * 32; i += 256) {
            const int h = i & 31, cc = (i >> 5) % 15, b = i / 480;
            float s = bk[cc];
            for (int ci = 0; ci < 15; ++ci) {
                #pragma unroll
                for (int kh = 0; kh < 3; ++kh) {
                    const int hh = h + kh - 1;
                    const float val = (hh >= 0 && hh < 32) ? fmaxf(r[b][ci][hh], 0.f) : 0.f;
                    s += wk[cc][ci][kh] * val;
                }
            }
            t[b][cc][h] = s;
        }
        __syncthreads();
        for (int i = tid; i < 8 * 15 * 32; i += 256) {
            const int h = i & 31, cc = (i >> 5) % 15, b = i / 480;
            r[b][cc][h] = t[b][cc][h];
        }
        __syncthreads();
    }

    // residual pyramid: H = 32,16,8,4  (ends at H=2)
    for (int H = 32; H > 2; H >>= 1) {
        const int Hh = H >> 1;
        // maxpool3 stride2 over bottom-padded column (pad value 0 participates)
        for (int i = tid; i < 8 * 15 * Hh; i += 256) {
            const int h = i % Hh, cc = (i / Hh) % 15, b = i / (15 * Hh);
            const float m0 = r[b][cc][2 * h], m1 = r[b][cc][2 * h + 1];
            const float m2 = (2 * h + 2 < H) ? r[b][cc][2 * h + 2] : 0.f;
            px[b][cc][h] = fmaxf(fmaxf(m0, m1), m2);
        }
        __syncthreads();
        // t = conv3(relu(pad(px)))
        for (int i = tid; i < 8 * 15 * Hh; i += 256) {
            const int h = i % Hh, cc = (i / Hh) % 15, b = i / (15 * Hh);
            float s = bk[cc];
            for (int ci = 0; ci < 15; ++ci) {
                #pragma unroll
                for (int kh = 0; kh < 3; ++kh) {
                    const int hh = h + kh - 1;
                    const float val = (hh >= 0 && hh < Hh) ? fmaxf(px[b][ci][hh], 0.f) : 0.f;
                    s += wk[cc][ci][kh] * val;
                }
            }
            t[b][cc][h] = s;
        }
        __syncthreads();
        // r = conv3(relu(pad(t))) + px
        for (int i = tid; i < 8 * 15 * Hh; i += 256) {
            const int h = i % Hh, cc = (i / Hh) % 15, b = i / (15 * Hh);
            float s = bk[cc];
            for (int ci = 0; ci < 15; ++ci) {
                #pragma unroll
                for (int kh = 0; kh < 3; ++kh) {
                    const int hh = h + kh - 1;
                    const float val = (hh >= 0 && hh < Hh) ? fmaxf(t[b][ci][hh], 0.f) : 0.f;
                    s += wk[cc][ci][kh] * val;
                }
            }
            r[b][cc][h] = s + px[b][cc][h];
        }
        __syncthreads();
    }

    // final linear: flat k = c*2 + h, out[b][o] = bout[o] + sum wout[o][k]*r[b][c][h]
    if (tid < 16) {
        const int b = tid >> 1, o = tid & 1;
        float s = bout[o];
        for (int c = 0; c < 15; ++c)
            #pragma unroll
            for (int h = 0; h < 2; ++h)
                s += wout[o * 30 + c * 2 + h] * r[b][c][h];
        out[b * 2 + o] = s;
    }
}

// ---------------------------------------------------------------------------
extern "C" void kernel_launch(void* const* d_in, const int* in_sizes, int n_in,
                              void* d_out, int out_size, void* d_ws, size_t ws_size,
                              hipStream_t stream)
{
    const float* x = (const float*)d_in[0];
    const float* w1 = (const float*)d_in[1];  const float* b1 = (const float*)d_in[2];
    const float* g1 = (const float*)d_in[3];  const float* be1 = (const float*)d_in[4];
    const float* m1 = (const float*)d_in[5];  const float* v1 = (const float*)d_in[6];
    const float* w2 = (const float*)d_in[7];  const float* b2 = (const float*)d_in[8];
    const float* g2 = (const float*)d_in[9];  const float* be2 = (const float*)d_in[10];
    const float* m2 = (const float*)d_in[11]; const float* v2 = (const float*)d_in[12];
    const float* w3 = (const float*)d_in[13]; const float* b3 = (const float*)d_in[14];
    const float* g3 = (const float*)d_in[15]; const float* be3 = (const float*)d_in[16];
    const float* m3 = (const float*)d_in[17]; const float* v3 = (const float*)d_in[18];
    const float* w4 = (const float*)d_in[19]; const float* b4 = (const float*)d_in[20];
    const float* g4 = (const float*)d_in[21]; const float* be4 = (const float*)d_in[22];
    const float* m4 = (const float*)d_in[23]; const float* v4 = (const float*)d_in[24];
    const float* wfc = (const float*)d_in[25]; const float* bfc = (const float*)d_in[26];
    const float* wc3 = (const float*)d_in[27]; const float* bc3 = (const float*)d_in[28];
    const float* wout = (const float*)d_in[29]; const float* bout = (const float*)d_in[30];
    float* out = (float*)d_out;

    (void)in_sizes; (void)n_in; (void)out_size;

    // --- workspace budget: res[3840] | A: G*200000 | B: G*100000 (floats) ---
    // G = largest divisor of 120 that fits in ws_size. Deterministic in
    // ws_size (constant across calls) -> identical work every launch.
    const size_t ws_floats = ws_size / 4;
    static const int divs[] = {120, 60, 40, 30, 24, 20, 15, 12, 10, 8, 6, 5, 4, 3, 2, 1};
    int G = 1;
    for (int i = 0; i < 16; ++i) {
        const size_t need = 3840 + (size_t)divs[i] * 300000;
        if (need <= ws_floats) { G = divs[i]; break; }
    }

    float* res  = (float*)d_ws;                // [120,32]
    float* bufA = res + 3840;                  // G*200000 floats
    float* bufB = bufA + (size_t)G * 200000;   // G*100000 floats

    for (int n0 = 0; n0 < 120; n0 += G) {
        float* c1o = bufA;                     // [G,16,50,250]
        float* c2o = bufB;                     // [G,32,25,125]
        float* c3o = bufA;                     // [G,64,12,62]
        float* c4o = bufB;                     // [G,32,6,31] == feats [G,5952]
        conv1_kernel<<<dim3(49, 16, G), 256, 0, stream>>>(
            x, w1, b1, g1, be1, m1, v1, c1o, n0);
        convblk_kernel<16, 32, 50, 250, 25, 125><<<dim3(13, 32, G), 256, 0, stream>>>(
            c1o, w2, b2, g2, be2, m2, v2, c2o);
        convblk_kernel<32, 64, 25, 125, 12, 62><<<dim3(3, 64, G), 256, 0, stream>>>(
            c2o, w3, b3, g3, be3, m3, v3, c3o);
        convblk_kernel<64, 32, 12, 62, 6, 31><<<dim3(1, 32, G), 256, 0, stream>>>(
            c3o, w4, b4, g4, be4, m4, v4, c4o);
        fc_kernel<<<dim3(G), 256, 0, stream>>>(c4o, wfc, bfc, res, n0);
    }
    dpcnn_kernel<<<dim3(1), 256, 0, stream>>>(res, wc3, bc3, wout, bout, out);
}

// Round 3
// 1693.344 us; speedup vs baseline: 4.3163x; 4.3163x over previous
//
#include <hip/hip_runtime.h>
#include <hip/hip_bf16.h>

#define EPS 1e-5f

// ---------------------------------------------------------------------------
// Stage 1: x [8,1,100,7500]; 120 chunks of [1,100,500].
// fused conv5x5(pad2, 1->16) + BN + ReLU + maxpool2x2 -> out [120,16,50,250]
// One thread computes ALL 16 output channels for one pooled pixel:
// 36 input loads amortized over 16*100 = 1600 MACs.
// ---------------------------------------------------------------------------
__global__ __launch_bounds__(256) void conv1_kernel(
    const float* __restrict__ x,
    const float* __restrict__ w, const float* __restrict__ bias,
    const float* __restrict__ g, const float* __restrict__ beta,
    const float* __restrict__ m, const float* __restrict__ v,
    float* __restrict__ out)
{
    __shared__ float wlds[16 * 25];
    __shared__ float scb[16], shb[16];
    const int n = blockIdx.z;                  // 0..119
    for (int i = threadIdx.x; i < 16 * 25; i += 256) wlds[i] = w[i];
    if (threadIdx.x < 16) {
        const int co = threadIdx.x;
        const float sc = g[co] / sqrtf(v[co] + EPS);
        scb[co] = sc;
        shb[co] = (bias[co] - m[co]) * sc + beta[co];
    }
    __syncthreads();

    const int sp = blockIdx.x * 256 + threadIdx.x;
    if (sp >= 50 * 250) return;
    const int ph = sp / 250, pw = sp % 250;
    const int b = n / 15, c = n % 15;
    const float* xb = x + (size_t)b * 100 * 7500 + (size_t)c * 500;

    const int y0 = 2 * ph - 2, x0 = 2 * pw - 2;
    float win[6][6];
    #pragma unroll
    for (int r = 0; r < 6; ++r) {
        const int y = y0 + r;
        const bool yv = (y >= 0 && y < 100);
        const float* row = xb + y * 7500;
        #pragma unroll
        for (int cc = 0; cc < 6; ++cc) {
            const int xx = x0 + cc;
            win[r][cc] = (yv && xx >= 0 && xx < 500) ? row[xx] : 0.f;
        }
    }

    #pragma unroll
    for (int oc = 0; oc < 16; ++oc) {
        const float* wc = &wlds[oc * 25];
        float a00 = 0.f, a01 = 0.f, a10 = 0.f, a11 = 0.f;
        #pragma unroll
        for (int kh = 0; kh < 5; ++kh)
            #pragma unroll
            for (int kw = 0; kw < 5; ++kw) {
                const float wv = wc[kh * 5 + kw];
                a00 += win[kh][kw] * wv;     a01 += win[kh][kw + 1] * wv;
                a10 += win[kh + 1][kw] * wv; a11 += win[kh + 1][kw + 1] * wv;
            }
        const float sc = scb[oc], sh = shb[oc];
        a00 = fmaxf(a00 * sc + sh, 0.f); a01 = fmaxf(a01 * sc + sh, 0.f);
        a10 = fmaxf(a10 * sc + sh, 0.f); a11 = fmaxf(a11 * sc + sh, 0.f);
        out[(((size_t)n * 16 + oc) * 50 + ph) * 250 + pw] =
            fmaxf(fmaxf(a00, a01), fmaxf(a10, a11));
    }
}

// ---------------------------------------------------------------------------
// Stages 2-4: fused conv5x5(pad2)+BN+ReLU+maxpool2x2(VALID)
// in [120,CI,H,W] -> out [120,CO,PH,PW].  Each thread computes NCO output
// channels for one pooled pixel: CI*36 loads amortized over NCO*CI*100 MACs.
// ---------------------------------------------------------------------------
template <int CI, int CO, int H, int W, int PH, int PW, int NCO>
__global__ __launch_bounds__(256) void convblk_kernel(
    const float* __restrict__ in,
    const float* __restrict__ w, const float* __restrict__ bias,
    const float* __restrict__ g, const float* __restrict__ beta,
    const float* __restrict__ m, const float* __restrict__ v,
    float* __restrict__ out)
{
    __shared__ float wlds[NCO * CI * 25];      // [oc][ci][25]
    __shared__ float scb[NCO], shb[NCO];
    const int n = blockIdx.z;
    const int co0 = blockIdx.y * NCO;
    for (int i = threadIdx.x; i < NCO * CI * 25; i += 256)
        wlds[i] = w[(size_t)co0 * CI * 25 + i];
    if (threadIdx.x < NCO) {
        const int co = co0 + threadIdx.x;
        const float sc = g[co] / sqrtf(v[co] + EPS);
        scb[threadIdx.x] = sc;
        shb[threadIdx.x] = (bias[co] - m[co]) * sc + beta[co];
    }
    __syncthreads();

    const int sp = blockIdx.x * 256 + threadIdx.x;
    if (sp >= PH * PW) return;
    const int ph = sp / PW, pw = sp % PW;
    const int y0 = 2 * ph - 2, x0 = 2 * pw - 2;
    const float* inb = in + (size_t)n * CI * H * W;

    float acc[NCO][4];
    #pragma unroll
    for (int oc = 0; oc < NCO; ++oc)
        #pragma unroll
        for (int q = 0; q < 4; ++q) acc[oc][q] = 0.f;

    for (int ci = 0; ci < CI; ++ci) {
        const float* inc = inb + (size_t)ci * H * W;
        float win[6][6];
        #pragma unroll
        for (int r = 0; r < 6; ++r) {
            const int y = y0 + r;
            const bool yv = (y >= 0 && y < H);
            const float* row = inc + y * W;
            #pragma unroll
            for (int cc = 0; cc < 6; ++cc) {
                const int xx = x0 + cc;
                win[r][cc] = (yv && xx >= 0 && xx < W) ? row[xx] : 0.f;
            }
        }
        #pragma unroll
        for (int oc = 0; oc < NCO; ++oc) {
            const float* wc = &wlds[(oc * CI + ci) * 25];
            #pragma unroll
            for (int kh = 0; kh < 5; ++kh)
                #pragma unroll
                for (int kw = 0; kw < 5; ++kw) {
                    const float wv = wc[kh * 5 + kw];
                    acc[oc][0] += win[kh][kw] * wv;
                    acc[oc][1] += win[kh][kw + 1] * wv;
                    acc[oc][2] += win[kh + 1][kw] * wv;
                    acc[oc][3] += win[kh + 1][kw + 1] * wv;
                }
        }
    }

    #pragma unroll
    for (int oc = 0; oc < NCO; ++oc) {
        const float sc = scb[oc], sh = shb[oc];
        const float a00 = fmaxf(acc[oc][0] * sc + sh, 0.f);
        const float a01 = fmaxf(acc[oc][1] * sc + sh, 0.f);
        const float a10 = fmaxf(acc[oc][2] * sc + sh, 0.f);
        const float a11 = fmaxf(acc[oc][3] * sc + sh, 0.f);
        out[(((size_t)n * CO + co0 + oc) * PH + ph) * PW + pw] =
            fmaxf(fmaxf(a00, a01), fmaxf(a10, a11));
    }
}

// ---------------------------------------------------------------------------
// FC: feats [120,5952] @ wfc[32,5952]^T + bfc -> res [120,32]
// one block per n; 4 waves; each wave does 8 outputs via shuffle reduction
// ---------------------------------------------------------------------------
__global__ __launch_bounds__(256) void fc_kernel(
    const float* __restrict__ feats, const float* __restrict__ wfc,
    const float* __restrict__ bfc, float* __restrict__ res)
{
    const int n = blockIdx.x;
    const int lane = threadIdx.x & 63;
    const int wave = threadIdx.x >> 6;
    const float4* f4 = (const float4*)(feats + (size_t)n * 5952);
    for (int o8 = 0; o8 < 8; ++o8) {
        const int o = wave * 8 + o8;
        const float4* w4 = (const float4*)(wfc + (size_t)o * 5952);
        float s = 0.f;
        for (int k = lane; k < 1488; k += 64) {
            const float4 a = f4[k], b = w4[k];
            s += a.x * b.x + a.y * b.y + a.z * b.z + a.w * b.w;
        }
        #pragma unroll
        for (int off = 32; off > 0; off >>= 1) s += __shfl_down(s, off, 64);
        if (lane == 0) res[n * 32 + o] = s + bfc[o];
    }
}

// ---------------------------------------------------------------------------
// DPCNN head, entirely in one block. res [120,32] -> out [8,2]
// ---------------------------------------------------------------------------
__global__ __launch_bounds__(256) void dpcnn_kernel(
    const float* __restrict__ res,
    const float* __restrict__ wc3, const float* __restrict__ bc3,
    const float* __restrict__ wout, const float* __restrict__ bout,
    float* __restrict__ out)
{
    __shared__ float r[8][15][32];
    __shared__ float t[8][15][32];
    __shared__ float px[8][15][16];
    __shared__ float wk[15][15][3];
    __shared__ float bk[15];

    const int tid = threadIdx.x;
    for (int i = tid; i < 15 * 15 * 3; i += 256) ((float*)wk)[i] = wc3[i];
    if (tid < 15) bk[tid] = bc3[tid];
    for (int i = tid; i < 8 * 15 * 32; i += 256) {
        const int h = i & 31, c = (i >> 5) % 15, b = i / 480;
        r[b][c][h] = res[i];
    }
    __syncthreads();

    for (int pass = 0; pass < 2; ++pass) {
        for (int i = tid; i < 8 * 15 * 32; i += 256) {
            const int h = i & 31, cc = (i >> 5) % 15, b = i / 480;
            float s = bk[cc];
            for (int ci = 0; ci < 15; ++ci) {
                #pragma unroll
                for (int kh = 0; kh < 3; ++kh) {
                    const int hh = h + kh - 1;
                    const float val = (hh >= 0 && hh < 32) ? fmaxf(r[b][ci][hh], 0.f) : 0.f;
                    s += wk[cc][ci][kh] * val;
                }
            }
            t[b][cc][h] = s;
        }
        __syncthreads();
        for (int i = tid; i < 8 * 15 * 32; i += 256) {
            const int h = i & 31, cc = (i >> 5) % 15, b = i / 480;
            r[b][cc][h] = t[b][cc][h];
        }
        __syncthreads();
    }

    for (int H = 32; H > 2; H >>= 1) {
        const int Hh = H >> 1;
        for (int i = tid; i < 8 * 15 * Hh; i += 256) {
            const int h = i % Hh, cc = (i / Hh) % 15, b = i / (15 * Hh);
            const float m0 = r[b][cc][2 * h], m1 = r[b][cc][2 * h + 1];
            const float m2 = (2 * h + 2 < H) ? r[b][cc][2 * h + 2] : 0.f;
            px[b][cc][h] = fmaxf(fmaxf(m0, m1), m2);
        }
        __syncthreads();
        for (int i = tid; i < 8 * 15 * Hh; i += 256) {
            const int h = i % Hh, cc = (i / Hh) % 15, b = i / (15 * Hh);
            float s = bk[cc];
            for (int ci = 0; ci < 15; ++ci) {
                #pragma unroll
                for (int kh = 0; kh < 3; ++kh) {
                    const int hh = h + kh - 1;
                    const float val = (hh >= 0 && hh < Hh) ? fmaxf(px[b][ci][hh], 0.f) : 0.f;
                    s += wk[cc][ci][kh] * val;
                }
            }
            t[b][cc][h] = s;
        }
        __syncthreads();
        for (int i = tid; i < 8 * 15 * Hh; i += 256) {
            const int h = i % Hh, cc = (i / Hh) % 15, b = i / (15 * Hh);
            float s = bk[cc];
            for (int ci = 0; ci < 15; ++ci) {
                #pragma unroll
                for (int kh = 0; kh < 3; ++kh) {
                    const int hh = h + kh - 1;
                    const float val = (hh >= 0 && hh < Hh) ? fmaxf(t[b][ci][hh], 0.f) : 0.f;
                    s += wk[cc][ci][kh] * val;
                }
            }
            r[b][cc][h] = s + px[b][cc][h];
        }
        __syncthreads();
    }

    if (tid < 16) {
        const int b = tid >> 1, o = tid & 1;
        float s = bout[o];
        for (int c = 0; c < 15; ++c)
            #pragma unroll
            for (int h = 0; h < 2; ++h)
                s += wout[o * 30 + c * 2 + h] * r[b][c][h];
        out[b * 2 + o] = s;
    }
}

// ---------------------------------------------------------------------------
extern "C" void kernel_launch(void* const* d_in, const int* in_sizes, int n_in,
                              void* d_out, int out_size, void* d_ws, size_t ws_size,
                              hipStream_t stream)
{
    const float* x = (const float*)d_in[0];
    const float* w1 = (const float*)d_in[1];  const float* b1 = (const float*)d_in[2];
    const float* g1 = (const float*)d_in[3];  const float* be1 = (const float*)d_in[4];
    const float* m1 = (const float*)d_in[5];  const float* v1 = (const float*)d_in[6];
    const float* w2 = (const float*)d_in[7];  const float* b2 = (const float*)d_in[8];
    const float* g2 = (const float*)d_in[9];  const float* be2 = (const float*)d_in[10];
    const float* m2 = (const float*)d_in[11]; const float* v2 = (const float*)d_in[12];
    const float* w3 = (const float*)d_in[13]; const float* b3 = (const float*)d_in[14];
    const float* g3 = (const float*)d_in[15]; const float* be3 = (const float*)d_in[16];
    const float* m3 = (const float*)d_in[17]; const float* v3 = (const float*)d_in[18];
    const float* w4 = (const float*)d_in[19]; const float* b4 = (const float*)d_in[20];
    const float* g4 = (const float*)d_in[21]; const float* be4 = (const float*)d_in[22];
    const float* m4 = (const float*)d_in[23]; const float* v4 = (const float*)d_in[24];
    const float* wfc = (const float*)d_in[25]; const float* bfc = (const float*)d_in[26];
    const float* wc3 = (const float*)d_in[27]; const float* bc3 = (const float*)d_in[28];
    const float* wout = (const float*)d_in[29]; const float* bout = (const float*)d_in[30];
    float* out = (float*)d_out;

    (void)in_sizes; (void)n_in; (void)out_size;

    // --- workspace: res[3840] | A: G*200000 | B: G*100000 (floats) ---
    const size_t ws_floats = ws_size / 4;
    static const int divs[] = {120, 60, 40, 30, 24, 20, 15, 12, 10, 8, 6, 5, 4, 3, 2, 1};
    int G = 1;
    for (int i = 0; i < 16; ++i) {
        const size_t need = 3840 + (size_t)divs[i] * 300000;
        if (need <= ws_floats) { G = divs[i]; break; }
    }

    float* res  = (float*)d_ws;                // [120,32]
    float* bufA = res + 3840;                  // G*200000 floats
    float* bufB = bufA + (size_t)G * 200000;   // G*100000 floats

    for (int n0 = 0; n0 < 120; n0 += G) {
        float* c1o = bufA;                     // [G,16,50,250]
        float* c2o = bufB;                     // [G,32,25,125]
        float* c3o = bufA;                     // [G,64,12,62]
        float* c4o = bufB;                     // [G,32,6,31] == feats [G,5952]
        // NOTE: kernels index by global n = n0 + blockIdx.z but write local nl.
        // With G==120 (observed ws fits), n0==0 and global==local.
        conv1_kernel<<<dim3(49, 1, G), 256, 0, stream>>>(
            x + (size_t)0, w1, b1, g1, be1, m1, v1, c1o - (size_t)0);
        convblk_kernel<16, 32, 50, 250, 25, 125, 8><<<dim3(13, 4, G), 256, 0, stream>>>(
            c1o, w2, b2, g2, be2, m2, v2, c2o);
        convblk_kernel<32, 64, 25, 125, 12, 62, 8><<<dim3(3, 8, G), 256, 0, stream>>>(
            c2o, w3, b3, g3, be3, m3, v3, c3o);
        convblk_kernel<64, 32, 12, 62, 6, 31, 4><<<dim3(1, 8, G), 256, 0, stream>>>(
            c3o, w4, b4, g4, be4, m4, v4, c4o);
        fc_kernel<<<dim3(G), 256, 0, stream>>>(c4o, wfc, bfc, res + (size_t)n0 * 32);
        // adjust x/chunk base for groups: conv1 uses blockIdx.z as local nl, so
        // pass offset via pointer arithmetic only valid when n0==0; for n0>0 the
        // chunk decomposition needs global n. Handled by forcing G==120 fallback:
        if (G != 120) break;  // safety: ws too small is unexpected; see below
    }
    // Fallback path if ws couldn't fit G=120 (never observed): run groups with
    // explicit global-n offset using the generic path.
    if (G != 120) {
        for (int n0 = 0; n0 < 120; n0 += G) {
            // re-run with per-group base: conv1 reads global chunk n0+nl
            // (conv1_kernel derives b,c from n = blockIdx.z only when n0==0,
            //  so emulate by passing shifted x pointer per 15-chunk boundary is
            //  not possible in general; instead use 1-group-at-a-time with z
            //  offset folded into x pointer when n0 is a multiple of 15)
            // Simple correct fallback: process one chunk at a time.
        }
        // Process chunks one-by-one, correctly, if workspace is tiny.
        for (int n = 0; n < 120; ++n) {
            const int b = n / 15, c = n % 15;
            const float* xn = x + (size_t)b * 100 * 7500 + (size_t)c * 500;
            // conv1 for single chunk: reuse kernel with z=1; its n=blockIdx.z=0
            // maps to b=0,c=0 so base pointer xn is exactly what it reads.
            float* c1o = bufA; float* c2o = bufB; float* c3o = bufA; float* c4o = bufB;
            conv1_kernel<<<dim3(49, 1, 1), 256, 0, stream>>>(
                xn, w1, b1, g1, be1, m1, v1, c1o);
            convblk_kernel<16, 32, 50, 250, 25, 125, 8><<<dim3(13, 4, 1), 256, 0, stream>>>(
                c1o, w2, b2, g2, be2, m2, v2, c2o);
            convblk_kernel<32, 64, 25, 125, 12, 62, 8><<<dim3(3, 8, 1), 256, 0, stream>>>(
                c2o, w3, b3, g3, be3, m3, v3, c3o);
            convblk_kernel<64, 32, 12, 62, 6, 31, 4><<<dim3(1, 8, 1), 256, 0, stream>>>(
                c3o, w4, b4, g4, be4, m4, v4, c4o);
            fc_kernel<<<dim3(1), 256, 0, stream>>>(c4o, wfc, bfc, res + (size_t)n * 32);
        }
    }
    dpcnn_kernel<<<dim3(1), 256, 0, stream>>>(res, wc3, bc3, wout, bout, out);
}

// Round 4
// 624.243 us; speedup vs baseline: 11.7085x; 2.7126x over previous
//
#include <hip/hip_runtime.h>
#include <hip/hip_bf16.h>

#define EPS 1e-5f

typedef short bf16x8 __attribute__((ext_vector_type(8)));
typedef float f32x4  __attribute__((ext_vector_type(4)));

__device__ __forceinline__ unsigned short f2bf(float f) {
    __hip_bfloat16 h = __float2bfloat16(f);
    return *(unsigned short*)&h;
}
__device__ __forceinline__ float bf2f(unsigned short u) {
    __hip_bfloat16 h = *(__hip_bfloat16*)&u;
    return __bfloat162float(h);
}

// ---------------------------------------------------------------------------
// prep: BN scale/shift for stages 2..4 into ws (sc|sh per stage, contiguous)
// layout: sc2[32] sh2[32] sc3[64] sh3[64] sc4[32] sh4[32]  (256 floats)
// ---------------------------------------------------------------------------
__global__ void prep_scsh(
    const float* g2, const float* be2, const float* m2, const float* v2, const float* b2,
    const float* g3, const float* be3, const float* m3, const float* v3, const float* b3,
    const float* g4, const float* be4, const float* m4, const float* v4, const float* b4,
    float* base)
{
    const int t = threadIdx.x;
    if (t < 32) {
        const float sc = g2[t] / sqrtf(v2[t] + EPS);
        base[t] = sc; base[32 + t] = (b2[t] - m2[t]) * sc + be2[t];
    } else if (t < 96) {
        const int c = t - 32;
        const float sc = g3[c] / sqrtf(v3[c] + EPS);
        base[64 + c] = sc; base[128 + c] = (b3[c] - m3[c]) * sc + be3[c];
    } else if (t < 128) {
        const int c = t - 96;
        const float sc = g4[c] / sqrtf(v4[c] + EPS);
        base[192 + c] = sc; base[224 + c] = (b4[c] - m4[c]) * sc + be4[c];
    }
}

// ---------------------------------------------------------------------------
// prep: pack conv weights into per-lane MFMA A-fragments (bf16).
// A_pk[((p*COTALL + cot)*64 + lane)*8 + j] = W[co][ci][kh][kw] where
// co = cot*16 + (lane&15); kidx = p*32 + (lane>>4)*8 + j; tap=kidx/CI; ci=kidx%CI
// ---------------------------------------------------------------------------
template <int CI, int CO, int NP>
__global__ void prep_A(const float* __restrict__ w, unsigned short* __restrict__ Apk)
{
    constexpr int COTALL = CO / 16;
    const int tot = NP * COTALL * 512;
    for (int i = blockIdx.x * 256 + threadIdx.x; i < tot; i += gridDim.x * 256) {
        const int j = i & 7, lane = (i >> 3) & 63, pc = i >> 9;
        const int p = pc / COTALL, cot = pc % COTALL;
        const int kidx = p * 32 + (lane >> 4) * 8 + j;
        const int tap = kidx / CI, ci = kidx % CI;
        const int co = cot * 16 + (lane & 15);
        const float val = (tap < 25) ? w[((size_t)co * CI + ci) * 25 + tap] : 0.f;
        Apk[i] = f2bf(val);
    }
}

// ---------------------------------------------------------------------------
// Stage 1 (fp32 vector): x [8,1,100,7500] -> c1o bf16 channels-last
// [120][50][250][16].  conv5x5(pad2,1->16)+BN+ReLU+pool2x2.
// ---------------------------------------------------------------------------
__global__ __launch_bounds__(256) void conv1_kernel(
    const float* __restrict__ x,
    const float* __restrict__ w, const float* __restrict__ bias,
    const float* __restrict__ g, const float* __restrict__ beta,
    const float* __restrict__ m, const float* __restrict__ v,
    unsigned short* __restrict__ out)
{
    __shared__ float wlds[16 * 25];
    __shared__ float scb[16], shb[16];
    const int n = blockIdx.z;
    for (int i = threadIdx.x; i < 16 * 25; i += 256) wlds[i] = w[i];
    if (threadIdx.x < 16) {
        const int co = threadIdx.x;
        const float sc = g[co] / sqrtf(v[co] + EPS);
        scb[co] = sc;
        shb[co] = (bias[co] - m[co]) * sc + beta[co];
    }
    __syncthreads();

    const int sp = blockIdx.x * 256 + threadIdx.x;
    if (sp >= 50 * 250) return;
    const int ph = sp / 250, pw = sp % 250;
    const int b = n / 15, c = n % 15;
    const float* xb = x + (size_t)b * 100 * 7500 + (size_t)c * 500;

    const int y0 = 2 * ph - 2, x0 = 2 * pw - 2;
    float win[6][6];
    #pragma unroll
    for (int r = 0; r < 6; ++r) {
        const int y = y0 + r;
        const bool yv = (y >= 0 && y < 100);
        const float* row = xb + y * 7500;
        #pragma unroll
        for (int cc = 0; cc < 6; ++cc) {
            const int xx = x0 + cc;
            win[r][cc] = (yv && xx >= 0 && xx < 500) ? row[xx] : 0.f;
        }
    }

    unsigned int packed[8];
    #pragma unroll
    for (int oc = 0; oc < 16; ++oc) {
        const float* wc = &wlds[oc * 25];
        float a00 = 0.f, a01 = 0.f, a10 = 0.f, a11 = 0.f;
        #pragma unroll
        for (int kh = 0; kh < 5; ++kh)
            #pragma unroll
            for (int kw = 0; kw < 5; ++kw) {
                const float wv = wc[kh * 5 + kw];
                a00 += win[kh][kw] * wv;     a01 += win[kh][kw + 1] * wv;
                a10 += win[kh + 1][kw] * wv; a11 += win[kh + 1][kw + 1] * wv;
            }
        const float sc = scb[oc], sh = shb[oc];
        a00 = fmaxf(a00 * sc + sh, 0.f); a01 = fmaxf(a01 * sc + sh, 0.f);
        a10 = fmaxf(a10 * sc + sh, 0.f); a11 = fmaxf(a11 * sc + sh, 0.f);
        const unsigned short bits = f2bf(fmaxf(fmaxf(a00, a01), fmaxf(a10, a11)));
        if (oc & 1) packed[oc >> 1] |= ((unsigned int)bits) << 16;
        else        packed[oc >> 1] = bits;
    }
    unsigned short* dst = out + (((size_t)n * 50 + ph) * 250 + pw) * 16;
    *(uint4*)(dst)     = make_uint4(packed[0], packed[1], packed[2], packed[3]);
    *(uint4*)(dst + 8) = make_uint4(packed[4], packed[5], packed[6], packed[7]);
}

// ---------------------------------------------------------------------------
// MFMA conv stage: in bf16 [N][H][W][CI] -> out bf16 [N][PH][PW][CO]
// conv5x5(pad2) + BN + ReLU + maxpool2x2, via mfma_f32_16x16x32_bf16.
// Block: (coltile TW=32, rowtile TH=8, n*COB + cob). 4 waves; wave w owns conv
// rows {2w,2w+1} -> pooled row py = by*4+w. Taps packed into MFMA K.
// LDS cell stride = CI*2+16 bytes (2-way bank aliasing only).
// ---------------------------------------------------------------------------
template <int CI, int CO, int H, int W, int PH, int PW, int NP>
__global__ __launch_bounds__(256) void mfma_conv(
    const unsigned short* __restrict__ in,
    const unsigned short* __restrict__ Apk,
    const float* __restrict__ sc, const float* __restrict__ sh,
    unsigned short* __restrict__ outp)
{
    constexpr int TH = 8, TW = 32, ROWS = TH + 4, COLS = TW + 4;
    constexpr int CSTR = CI * 2 + 16;            // bytes per (y,x) cell
    constexpr int COTALL = CO / 16, COB = CO / 32;
    constexpr int CPC = CI / 8;                  // 16B chunks per cell
    __shared__ char smem[ROWS * COLS * CSTR];

    const int n = blockIdx.z / COB, cob = blockIdx.z % COB;
    const int ytile = blockIdx.y * TH, xtile = blockIdx.x * TW;
    const int tid = threadIdx.x;

    // ---- stage input tile (zero-padded) ----
    for (int i = tid; i < ROWS * COLS * CPC; i += 256) {
        const int cell = i / CPC, ch = i % CPC;
        const int yy = cell / COLS, xx = cell % COLS;
        const int gy = ytile - 2 + yy, gx = xtile - 2 + xx;
        uint4 val = make_uint4(0, 0, 0, 0);
        if (gy >= 0 && gy < H && gx >= 0 && gx < W)
            val = *(const uint4*)(in + ((((size_t)n * H + gy) * W + gx) * CI + ch * 8));
        *(uint4*)(smem + (size_t)(yy * COLS + xx) * CSTR + ch * 16) = val;
    }
    __syncthreads();

    const int lane = tid & 63, wav = tid >> 6;
    const int g = lane >> 4, c15 = lane & 15;
    const int laneCi = (CI == 16) ? ((g & 1) * 16) : (g * 16);
    const bool hi = (lane >= 32);

    int baddr[2][2];
    #pragma unroll
    for (int r = 0; r < 2; ++r)
        #pragma unroll
        for (int cg = 0; cg < 2; ++cg)
            baddr[r][cg] = ((wav * 2 + r) * COLS + cg * 16 + c15) * CSTR + laneCi;

    f32x4 acc[2][2][2] = {};                     // [row r][co-tile ct][colgrp cg]

    #pragma unroll
    for (int p = 0; p < NP; ++p) {
        int D;
        if (CI == 16) {
            int t0 = p * 2;     if (t0 > 24) t0 = 24;
            int t1 = p * 2 + 1; if (t1 > 24) t1 = 24;
            const int D0 = ((t0 / 5) * COLS + t0 % 5) * CSTR;
            const int D1 = ((t1 / 5) * COLS + t1 % 5) * CSTR;
            D = hi ? D1 : D0;
        } else {
            const int tap = (CI == 32) ? p : (p >> 1);
            D = ((tap / 5) * COLS + tap % 5) * CSTR + ((CI == 64) ? (p & 1) * 64 : 0);
        }
        bf16x8 a[2], b[2][2];
        #pragma unroll
        for (int ct = 0; ct < 2; ++ct)
            a[ct] = *(const bf16x8*)(Apk + ((size_t)(p * COTALL + cob * 2 + ct) * 64 + lane) * 8);
        #pragma unroll
        for (int r = 0; r < 2; ++r)
            #pragma unroll
            for (int cg = 0; cg < 2; ++cg)
                b[r][cg] = *(const bf16x8*)(smem + baddr[r][cg] + D);
        #pragma unroll
        for (int r = 0; r < 2; ++r)
            #pragma unroll
            for (int ct = 0; ct < 2; ++ct)
                #pragma unroll
                for (int cg = 0; cg < 2; ++cg)
                    acc[r][ct][cg] = __builtin_amdgcn_mfma_f32_16x16x32_bf16(
                        a[ct], b[r][cg], acc[r][ct][cg], 0, 0, 0);
    }

    // ---- epilogue: BN + ReLU + 2x2 maxpool + bf16 store (channels-last) ----
    const int py = blockIdx.y * 4 + wav;
    #pragma unroll
    for (int ct = 0; ct < 2; ++ct) {
        const int coW = cob * 32 + ct * 16;
        const float4 scv = *(const float4*)(sc + coW + g * 4);
        const float4 shv = *(const float4*)(sh + coW + g * 4);
        #pragma unroll
        for (int cg = 0; cg < 2; ++cg) {
            const int px = (xtile >> 1) + cg * 8 + (c15 >> 1);
            ushort4 st;
            #pragma unroll
            for (int reg = 0; reg < 4; ++reg) {
                const float scr = (&scv.x)[reg], shr = (&shv.x)[reg];
                const float v0 = fmaxf(acc[0][ct][cg][reg] * scr + shr, 0.f);
                const float v1 = fmaxf(acc[1][ct][cg][reg] * scr + shr, 0.f);
                float mx = fmaxf(v0, v1);
                mx = fmaxf(mx, __shfl_xor(mx, 1));
                (&st.x)[reg] = f2bf(mx);
            }
            if ((lane & 1) == 0 && py < PH && px < PW)
                *(ushort4*)(outp + (((size_t)n * PH + py) * PW + px) * CO + coW + g * 4) = st;
        }
    }
}

// ---------------------------------------------------------------------------
// FC: feats bf16 channels-last [120][6][31][32] @ wfc[32][5952]^T + bfc -> res f32
// flat feat index j = (y*31+x)*32 + c ; torch k = c*186 + (y*31+x)
// ---------------------------------------------------------------------------
__global__ __launch_bounds__(256) void fc_kernel(
    const unsigned short* __restrict__ feats, const float* __restrict__ wfc,
    const float* __restrict__ bfc, float* __restrict__ res)
{
    const int n = blockIdx.x;
    const int lane = threadIdx.x & 63;
    const int wave = threadIdx.x >> 6;
    const unsigned short* f = feats + (size_t)n * 5952;
    for (int o8 = 0; o8 < 8; ++o8) {
        const int o = wave * 8 + o8;
        const float* wr = wfc + (size_t)o * 5952;
        float s = 0.f;
        for (int j = lane; j < 5952; j += 64) {
            const int c = j & 31, yx = j >> 5;
            s += bf2f(f[j]) * wr[c * 186 + yx];
        }
        #pragma unroll
        for (int off = 32; off > 0; off >>= 1) s += __shfl_down(s, off, 64);
        if (lane == 0) res[n * 32 + o] = s + bfc[o];
    }
}

// ---------------------------------------------------------------------------
// DPCNN head, one block. res f32 [120,32] -> out [8,2]
// ---------------------------------------------------------------------------
__global__ __launch_bounds__(256) void dpcnn_kernel(
    const float* __restrict__ res,
    const float* __restrict__ wc3, const float* __restrict__ bc3,
    const float* __restrict__ wout, const float* __restrict__ bout,
    float* __restrict__ out)
{
    __shared__ float r[8][15][32];
    __shared__ float t[8][15][32];
    __shared__ float px[8][15][16];
    __shared__ float wk[15][15][3];
    __shared__ float bk[15];

    const int tid = threadIdx.x;
    for (int i = tid; i < 15 * 15 * 3; i += 256) ((float*)wk)[i] = wc3[i];
    if (tid < 15) bk[tid] = bc3[tid];
    for (int i = tid; i < 8 * 15 * 32; i += 256) {
        const int h = i & 31, c = (i >> 5) % 15, b = i / 480;
        r[b][c][h] = res[i];
    }
    __syncthreads();

    for (int pass = 0; pass < 2; ++pass) {
        for (int i = tid; i < 8 * 15 * 32; i += 256) {
            const int h = i & 31, cc = (i >> 5) % 15, b = i / 480;
            float s = bk[cc];
            for (int ci = 0; ci < 15; ++ci) {
                #pragma unroll
                for (int kh = 0; kh < 3; ++kh) {
                    const int hh = h + kh - 1;
                    const float val = (hh >= 0 && hh < 32) ? fmaxf(r[b][ci][hh], 0.f) : 0.f;
                    s += wk[cc][ci][kh] * val;
                }
            }
            t[b][cc][h] = s;
        }
        __syncthreads();
        for (int i = tid; i < 8 * 15 * 32; i += 256) {
            const int h = i & 31, cc = (i >> 5) % 15, b = i / 480;
            r[b][cc][h] = t[b][cc][h];
        }
        __syncthreads();
    }

    for (int H = 32; H > 2; H >>= 1) {
        const int Hh = H >> 1;
        for (int i = tid; i < 8 * 15 * Hh; i += 256) {
            const int h = i % Hh, cc = (i / Hh) % 15, b = i / (15 * Hh);
            const float m0 = r[b][cc][2 * h], m1 = r[b][cc][2 * h + 1];
            const float m2 = (2 * h + 2 < H) ? r[b][cc][2 * h + 2] : 0.f;
            px[b][cc][h] = fmaxf(fmaxf(m0, m1), m2);
        }
        __syncthreads();
        for (int i = tid; i < 8 * 15 * Hh; i += 256) {
            const int h = i % Hh, cc = (i / Hh) % 15, b = i / (15 * Hh);
            float s = bk[cc];
            for (int ci = 0; ci < 15; ++ci) {
                #pragma unroll
                for (int kh = 0; kh < 3; ++kh) {
                    const int hh = h + kh - 1;
                    const float val = (hh >= 0 && hh < Hh) ? fmaxf(px[b][ci][hh], 0.f) : 0.f;
                    s += wk[cc][ci][kh] * val;
                }
            }
            t[b][cc][h] = s;
        }
        __syncthreads();
        for (int i = tid; i < 8 * 15 * Hh; i += 256) {
            const int h = i % Hh, cc = (i / Hh) % 15, b = i / (15 * Hh);
            float s = bk[cc];
            for (int ci = 0; ci < 15; ++ci) {
                #pragma unroll
                for (int kh = 0; kh < 3; ++kh) {
                    const int hh = h + kh - 1;
                    const float val = (hh >= 0 && hh < Hh) ? fmaxf(t[b][ci][hh], 0.f) : 0.f;
                    s += wk[cc][ci][kh] * val;
                }
            }
            r[b][cc][h] = s + px[b][cc][h];
        }
        __syncthreads();
    }

    if (tid < 16) {
        const int b = tid >> 1, o = tid & 1;
        float s = bout[o];
        for (int c = 0; c < 15; ++c)
            #pragma unroll
            for (int h = 0; h < 2; ++h)
                s += wout[o * 30 + c * 2 + h] * r[b][c][h];
        out[b * 2 + o] = s;
    }
}

// ---------------------------------------------------------------------------
extern "C" void kernel_launch(void* const* d_in, const int* in_sizes, int n_in,
                              void* d_out, int out_size, void* d_ws, size_t ws_size,
                              hipStream_t stream)
{
    const float* x = (const float*)d_in[0];
    const float* w1 = (const float*)d_in[1];  const float* b1 = (const float*)d_in[2];
    const float* g1 = (const float*)d_in[3];  const float* be1 = (const float*)d_in[4];
    const float* m1 = (const float*)d_in[5];  const float* v1 = (const float*)d_in[6];
    const float* w2 = (const float*)d_in[7];  const float* b2 = (const float*)d_in[8];
    const float* g2 = (const float*)d_in[9];  const float* be2 = (const float*)d_in[10];
    const float* m2 = (const float*)d_in[11]; const float* v2 = (const float*)d_in[12];
    const float* w3 = (const float*)d_in[13]; const float* b3 = (const float*)d_in[14];
    const float* g3 = (const float*)d_in[15]; const float* be3 = (const float*)d_in[16];
    const float* m3 = (const float*)d_in[17]; const float* v3 = (const float*)d_in[18];
    const float* w4 = (const float*)d_in[19]; const float* b4 = (const float*)d_in[20];
    const float* g4 = (const float*)d_in[21]; const float* be4 = (const float*)d_in[22];
    const float* m4 = (const float*)d_in[23]; const float* v4 = (const float*)d_in[24];
    const float* wfc = (const float*)d_in[25]; const float* bfc = (const float*)d_in[26];
    const float* wc3 = (const float*)d_in[27]; const float* bc3 = (const float*)d_in[28];
    const float* wout = (const float*)d_in[29]; const float* bout = (const float*)d_in[30];
    float* out = (float*)d_out;

    (void)in_sizes; (void)n_in; (void)out_size; (void)ws_size;

    // ---- workspace layout (floats) ----
    float* wsf = (float*)d_ws;
    float* res   = wsf;                               // [120*32]
    float* scsh  = wsf + 3840;                        // 256 floats
    float* sc2 = scsh, *sh2 = scsh + 32;
    float* sc3 = scsh + 64, *sh3 = scsh + 128;
    float* sc4 = scsh + 192, *sh4 = scsh + 224;
    unsigned short* A2  = (unsigned short*)(wsf + 4096);      // 13312 us
    unsigned short* A3  = (unsigned short*)(wsf + 10752);     // 51200 us
    unsigned short* A4  = (unsigned short*)(wsf + 36352);     // 51200 us
    unsigned short* c1o = (unsigned short*)(wsf + 61952);     // [120][50][250][16]
    unsigned short* c2o = (unsigned short*)(wsf + 12061952);  // [120][25][125][32]
    unsigned short* c3o = (unsigned short*)(wsf + 18061952);  // [120][12][62][64]
    unsigned short* c4o = (unsigned short*)(wsf + 20918912);  // [120][6][31][32]

    // ---- prep ----
    prep_scsh<<<1, 256, 0, stream>>>(g2, be2, m2, v2, b2,
                                     g3, be3, m3, v3, b3,
                                     g4, be4, m4, v4, b4, scsh);
    prep_A<16, 32, 13><<<52, 256, 0, stream>>>(w2, A2);
    prep_A<32, 64, 25><<<200, 256, 0, stream>>>(w3, A3);
    prep_A<64, 32, 50><<<200, 256, 0, stream>>>(w4, A4);

    // ---- pipeline ----
    conv1_kernel<<<dim3(49, 1, 120), 256, 0, stream>>>(
        x, w1, b1, g1, be1, m1, v1, c1o);
    mfma_conv<16, 32, 50, 250, 25, 125, 13><<<dim3(8, 7, 120), 256, 0, stream>>>(
        c1o, A2, sc2, sh2, c2o);
    mfma_conv<32, 64, 25, 125, 12, 62, 25><<<dim3(4, 3, 240), 256, 0, stream>>>(
        c2o, A3, sc3, sh3, c3o);
    mfma_conv<64, 32, 12, 62, 6, 31, 50><<<dim3(2, 2, 120), 256, 0, stream>>>(
        c3o, A4, sc4, sh4, c4o);
    fc_kernel<<<dim3(120), 256, 0, stream>>>(c4o, wfc, bfc, res);
    dpcnn_kernel<<<dim3(1), 256, 0, stream>>>(res, wc3, bc3, wout, bout, out);
}

// Round 5
// 452.118 us; speedup vs baseline: 16.1660x; 1.3807x over previous
//
#include <hip/hip_runtime.h>
#include <hip/hip_bf16.h>

#define EPS 1e-5f

typedef short bf16x8 __attribute__((ext_vector_type(8)));
typedef float f32x4  __attribute__((ext_vector_type(4)));

__device__ __forceinline__ unsigned short f2bf(float f) {
    __hip_bfloat16 h = __float2bfloat16(f);
    return *(unsigned short*)&h;
}
__device__ __forceinline__ float bf2f(unsigned short u) {
    __hip_bfloat16 h = *(__hip_bfloat16*)&u;
    return __bfloat162float(h);
}

// ---------------------------------------------------------------------------
// prep: BN scale/shift for stages 2..4 into ws (sc|sh per stage, contiguous)
// layout: sc2[32] sh2[32] sc3[64] sh3[64] sc4[32] sh4[32]  (256 floats)
// ---------------------------------------------------------------------------
__global__ void prep_scsh(
    const float* g2, const float* be2, const float* m2, const float* v2, const float* b2,
    const float* g3, const float* be3, const float* m3, const float* v3, const float* b3,
    const float* g4, const float* be4, const float* m4, const float* v4, const float* b4,
    float* base)
{
    const int t = threadIdx.x;
    if (t < 32) {
        const float sc = g2[t] / sqrtf(v2[t] + EPS);
        base[t] = sc; base[32 + t] = (b2[t] - m2[t]) * sc + be2[t];
    } else if (t < 96) {
        const int c = t - 32;
        const float sc = g3[c] / sqrtf(v3[c] + EPS);
        base[64 + c] = sc; base[128 + c] = (b3[c] - m3[c]) * sc + be3[c];
    } else if (t < 128) {
        const int c = t - 96;
        const float sc = g4[c] / sqrtf(v4[c] + EPS);
        base[192 + c] = sc; base[224 + c] = (b4[c] - m4[c]) * sc + be4[c];
    }
}

// ---------------------------------------------------------------------------
// prep: pack conv weights into per-lane MFMA A-fragments (bf16).
// A_pk[((p*COTALL + cot)*64 + lane)*8 + j] = W[co][ci][kh][kw] where
// co = cot*16 + (lane&15); kidx = p*32 + (lane>>4)*8 + j; tap=kidx/CI; ci=kidx%CI
// ---------------------------------------------------------------------------
template <int CI, int CO, int NP>
__global__ void prep_A(const float* __restrict__ w, unsigned short* __restrict__ Apk)
{
    constexpr int COTALL = CO / 16;
    const int tot = NP * COTALL * 512;
    for (int i = blockIdx.x * 256 + threadIdx.x; i < tot; i += gridDim.x * 256) {
        const int j = i & 7, lane = (i >> 3) & 63, pc = i >> 9;
        const int p = pc / COTALL, cot = pc % COTALL;
        const int kidx = p * 32 + (lane >> 4) * 8 + j;
        const int tap = kidx / CI, ci = kidx % CI;
        const int co = cot * 16 + (lane & 15);
        const float val = (tap < 25) ? w[((size_t)co * CI + ci) * 25 + tap] : 0.f;
        Apk[i] = f2bf(val);
    }
}

// ---------------------------------------------------------------------------
// prep: permute+cast FC weight to match channels-last feats order.
// wfcT[o][j] = bf16(wfc[o][c*186 + yx])  where j = yx*32 + c
// ---------------------------------------------------------------------------
__global__ void prep_fcw(const float* __restrict__ wfc, unsigned short* __restrict__ wfcT)
{
    for (int i = blockIdx.x * 256 + threadIdx.x; i < 32 * 5952; i += gridDim.x * 256) {
        const int o = i / 5952, j = i % 5952;
        const int c = j & 31, yx = j >> 5;
        wfcT[i] = f2bf(wfc[(size_t)o * 5952 + c * 186 + yx]);
    }
}

// ---------------------------------------------------------------------------
// Stage 1 (fp32 vector): x [8,1,100,7500] -> c1o bf16 channels-last
// [120][50][250][16].  conv5x5(pad2,1->16)+BN+ReLU+pool2x2.
// ---------------------------------------------------------------------------
__global__ __launch_bounds__(256) void conv1_kernel(
    const float* __restrict__ x,
    const float* __restrict__ w, const float* __restrict__ bias,
    const float* __restrict__ g, const float* __restrict__ beta,
    const float* __restrict__ m, const float* __restrict__ v,
    unsigned short* __restrict__ out)
{
    __shared__ float wlds[16 * 25];
    __shared__ float scb[16], shb[16];
    const int n = blockIdx.z;
    for (int i = threadIdx.x; i < 16 * 25; i += 256) wlds[i] = w[i];
    if (threadIdx.x < 16) {
        const int co = threadIdx.x;
        const float sc = g[co] / sqrtf(v[co] + EPS);
        scb[co] = sc;
        shb[co] = (bias[co] - m[co]) * sc + beta[co];
    }
    __syncthreads();

    const int sp = blockIdx.x * 256 + threadIdx.x;
    if (sp >= 50 * 250) return;
    const int ph = sp / 250, pw = sp % 250;
    const int b = n / 15, c = n % 15;
    const float* xb = x + (size_t)b * 100 * 7500 + (size_t)c * 500;

    const int y0 = 2 * ph - 2, x0 = 2 * pw - 2;
    float win[6][6];
    #pragma unroll
    for (int r = 0; r < 6; ++r) {
        const int y = y0 + r;
        const bool yv = (y >= 0 && y < 100);
        const float* row = xb + y * 7500;
        #pragma unroll
        for (int cc = 0; cc < 6; ++cc) {
            const int xx = x0 + cc;
            win[r][cc] = (yv && xx >= 0 && xx < 500) ? row[xx] : 0.f;
        }
    }

    unsigned int packed[8];
    #pragma unroll
    for (int oc = 0; oc < 16; ++oc) {
        const float* wc = &wlds[oc * 25];
        float a00 = 0.f, a01 = 0.f, a10 = 0.f, a11 = 0.f;
        #pragma unroll
        for (int kh = 0; kh < 5; ++kh)
            #pragma unroll
            for (int kw = 0; kw < 5; ++kw) {
                const float wv = wc[kh * 5 + kw];
                a00 += win[kh][kw] * wv;     a01 += win[kh][kw + 1] * wv;
                a10 += win[kh + 1][kw] * wv; a11 += win[kh + 1][kw + 1] * wv;
            }
        const float sc = scb[oc], sh = shb[oc];
        a00 = fmaxf(a00 * sc + sh, 0.f); a01 = fmaxf(a01 * sc + sh, 0.f);
        a10 = fmaxf(a10 * sc + sh, 0.f); a11 = fmaxf(a11 * sc + sh, 0.f);
        const unsigned short bits = f2bf(fmaxf(fmaxf(a00, a01), fmaxf(a10, a11)));
        if (oc & 1) packed[oc >> 1] |= ((unsigned int)bits) << 16;
        else        packed[oc >> 1] = bits;
    }
    unsigned short* dst = out + (((size_t)n * 50 + ph) * 250 + pw) * 16;
    *(uint4*)(dst)     = make_uint4(packed[0], packed[1], packed[2], packed[3]);
    *(uint4*)(dst + 8) = make_uint4(packed[4], packed[5], packed[6], packed[7]);
}

// ---------------------------------------------------------------------------
// MFMA conv stage: in bf16 [N][H][W][CI] -> out bf16 [N][PH][PW][CO]
// conv5x5(pad2) + BN + ReLU + maxpool2x2, via mfma_f32_16x16x32_bf16.
// ---------------------------------------------------------------------------
template <int CI, int CO, int H, int W, int PH, int PW, int NP>
__global__ __launch_bounds__(256) void mfma_conv(
    const unsigned short* __restrict__ in,
    const unsigned short* __restrict__ Apk,
    const float* __restrict__ sc, const float* __restrict__ sh,
    unsigned short* __restrict__ outp)
{
    constexpr int TH = 8, TW = 32, ROWS = TH + 4, COLS = TW + 4;
    constexpr int CSTR = CI * 2 + 16;            // bytes per (y,x) cell
    constexpr int COTALL = CO / 16, COB = CO / 32;
    constexpr int CPC = CI / 8;                  // 16B chunks per cell
    __shared__ char smem[ROWS * COLS * CSTR];

    const int n = blockIdx.z / COB, cob = blockIdx.z % COB;
    const int ytile = blockIdx.y * TH, xtile = blockIdx.x * TW;
    const int tid = threadIdx.x;

    // ---- stage input tile (zero-padded) ----
    for (int i = tid; i < ROWS * COLS * CPC; i += 256) {
        const int cell = i / CPC, ch = i % CPC;
        const int yy = cell / COLS, xx = cell % COLS;
        const int gy = ytile - 2 + yy, gx = xtile - 2 + xx;
        uint4 val = make_uint4(0, 0, 0, 0);
        if (gy >= 0 && gy < H && gx >= 0 && gx < W)
            val = *(const uint4*)(in + ((((size_t)n * H + gy) * W + gx) * CI + ch * 8));
        *(uint4*)(smem + (size_t)(yy * COLS + xx) * CSTR + ch * 16) = val;
    }
    __syncthreads();

    const int lane = tid & 63, wav = tid >> 6;
    const int g = lane >> 4, c15 = lane & 15;
    const int laneCi = (CI == 16) ? ((g & 1) * 16) : (g * 16);
    const bool hi = (lane >= 32);

    int baddr[2][2];
    #pragma unroll
    for (int r = 0; r < 2; ++r)
        #pragma unroll
        for (int cg = 0; cg < 2; ++cg)
            baddr[r][cg] = ((wav * 2 + r) * COLS + cg * 16 + c15) * CSTR + laneCi;

    f32x4 acc[2][2][2] = {};                     // [row r][co-tile ct][colgrp cg]

    #pragma unroll
    for (int p = 0; p < NP; ++p) {
        int D;
        if (CI == 16) {
            int t0 = p * 2;     if (t0 > 24) t0 = 24;
            int t1 = p * 2 + 1; if (t1 > 24) t1 = 24;
            const int D0 = ((t0 / 5) * COLS + t0 % 5) * CSTR;
            const int D1 = ((t1 / 5) * COLS + t1 % 5) * CSTR;
            D = hi ? D1 : D0;
        } else {
            const int tap = (CI == 32) ? p : (p >> 1);
            D = ((tap / 5) * COLS + tap % 5) * CSTR + ((CI == 64) ? (p & 1) * 64 : 0);
        }
        bf16x8 a[2], b[2][2];
        #pragma unroll
        for (int ct = 0; ct < 2; ++ct)
            a[ct] = *(const bf16x8*)(Apk + ((size_t)(p * COTALL + cob * 2 + ct) * 64 + lane) * 8);
        #pragma unroll
        for (int r = 0; r < 2; ++r)
            #pragma unroll
            for (int cg = 0; cg < 2; ++cg)
                b[r][cg] = *(const bf16x8*)(smem + baddr[r][cg] + D);
        #pragma unroll
        for (int r = 0; r < 2; ++r)
            #pragma unroll
            for (int ct = 0; ct < 2; ++ct)
                #pragma unroll
                for (int cg = 0; cg < 2; ++cg)
                    acc[r][ct][cg] = __builtin_amdgcn_mfma_f32_16x16x32_bf16(
                        a[ct], b[r][cg], acc[r][ct][cg], 0, 0, 0);
    }

    // ---- epilogue: BN + ReLU + 2x2 maxpool + bf16 store (channels-last) ----
    const int py = blockIdx.y * 4 + wav;
    #pragma unroll
    for (int ct = 0; ct < 2; ++ct) {
        const int coW = cob * 32 + ct * 16;
        const float4 scv = *(const float4*)(sc + coW + g * 4);
        const float4 shv = *(const float4*)(sh + coW + g * 4);
        #pragma unroll
        for (int cg = 0; cg < 2; ++cg) {
            const int px = (xtile >> 1) + cg * 8 + (c15 >> 1);
            ushort4 st;
            #pragma unroll
            for (int reg = 0; reg < 4; ++reg) {
                const float scr = (&scv.x)[reg], shr = (&shv.x)[reg];
                const float v0 = fmaxf(acc[0][ct][cg][reg] * scr + shr, 0.f);
                const float v1 = fmaxf(acc[1][ct][cg][reg] * scr + shr, 0.f);
                float mx = fmaxf(v0, v1);
                mx = fmaxf(mx, __shfl_xor(mx, 1));
                (&st.x)[reg] = f2bf(mx);
            }
            if ((lane & 1) == 0 && py < PH && px < PW)
                *(ushort4*)(outp + (((size_t)n * PH + py) * PW + px) * CO + coW + g * 4) = st;
        }
    }
}

// ---------------------------------------------------------------------------
// FC: feats bf16 [120][5952] (channels-last flat) . wfcT bf16 [32][5952]
// (pre-permuted to the same j-order) + bfc -> res f32 [120,32]
// Coalesced bf16x8 loads; 4 waves x 8 outputs per block.
// ---------------------------------------------------------------------------
__global__ __launch_bounds__(256) void fc_kernel(
    const unsigned short* __restrict__ feats, const unsigned short* __restrict__ wfcT,
    const float* __restrict__ bfc, float* __restrict__ res)
{
    const int n = blockIdx.x;
    const int lane = threadIdx.x & 63;
    const int wave = threadIdx.x >> 6;
    const unsigned short* f = feats + (size_t)n * 5952;
    #pragma unroll
    for (int o8 = 0; o8 < 8; ++o8) {
        const int o = wave * 8 + o8;
        const unsigned short* wr = wfcT + (size_t)o * 5952;
        float s = 0.f;
        #pragma unroll
        for (int i = 0; i < 12; ++i) {
            const int j8 = (i * 64 + lane) * 8;
            if (j8 < 5952) {
                const bf16x8 fv = *(const bf16x8*)(f + j8);
                const bf16x8 wv = *(const bf16x8*)(wr + j8);
                #pragma unroll
                for (int q = 0; q < 8; ++q)
                    s += bf2f(((const unsigned short*)&fv)[q]) *
                         bf2f(((const unsigned short*)&wv)[q]);
            }
        }
        #pragma unroll
        for (int off = 32; off > 0; off >>= 1) s += __shfl_down(s, off, 64);
        if (lane == 0) res[n * 32 + o] = s + bfc[o];
    }
}

// ---------------------------------------------------------------------------
// DPCNN head, one block. res f32 [120,32] -> out [8,2]
// ---------------------------------------------------------------------------
__global__ __launch_bounds__(256) void dpcnn_kernel(
    const float* __restrict__ res,
    const float* __restrict__ wc3, const float* __restrict__ bc3,
    const float* __restrict__ wout, const float* __restrict__ bout,
    float* __restrict__ out)
{
    __shared__ float r[8][15][32];
    __shared__ float t[8][15][32];
    __shared__ float px[8][15][16];
    __shared__ float wk[15][15][3];
    __shared__ float bk[15];

    const int tid = threadIdx.x;
    for (int i = tid; i < 15 * 15 * 3; i += 256) ((float*)wk)[i] = wc3[i];
    if (tid < 15) bk[tid] = bc3[tid];
    for (int i = tid; i < 8 * 15 * 32; i += 256) {
        const int h = i & 31, c = (i >> 5) % 15, b = i / 480;
        r[b][c][h] = res[i];
    }
    __syncthreads();

    for (int pass = 0; pass < 2; ++pass) {
        for (int i = tid; i < 8 * 15 * 32; i += 256) {
            const int h = i & 31, cc = (i >> 5) % 15, b = i / 480;
            float s = bk[cc];
            for (int ci = 0; ci < 15; ++ci) {
                #pragma unroll
                for (int kh = 0; kh < 3; ++kh) {
                    const int hh = h + kh - 1;
                    const float val = (hh >= 0 && hh < 32) ? fmaxf(r[b][ci][hh], 0.f) : 0.f;
                    s += wk[cc][ci][kh] * val;
                }
            }
            t[b][cc][h] = s;
        }
        __syncthreads();
        for (int i = tid; i < 8 * 15 * 32; i += 256) {
            const int h = i & 31, cc = (i >> 5) % 15, b = i / 480;
            r[b][cc][h] = t[b][cc][h];
        }
        __syncthreads();
    }

    for (int H = 32; H > 2; H >>= 1) {
        const int Hh = H >> 1;
        for (int i = tid; i < 8 * 15 * Hh; i += 256) {
            const int h = i % Hh, cc = (i / Hh) % 15, b = i / (15 * Hh);
            const float m0 = r[b][cc][2 * h], m1 = r[b][cc][2 * h + 1];
            const float m2 = (2 * h + 2 < H) ? r[b][cc][2 * h + 2] : 0.f;
            px[b][cc][h] = fmaxf(fmaxf(m0, m1), m2);
        }
        __syncthreads();
        for (int i = tid; i < 8 * 15 * Hh; i += 256) {
            const int h = i % Hh, cc = (i / Hh) % 15, b = i / (15 * Hh);
            float s = bk[cc];
            for (int ci = 0; ci < 15; ++ci) {
                #pragma unroll
                for (int kh = 0; kh < 3; ++kh) {
                    const int hh = h + kh - 1;
                    const float val = (hh >= 0 && hh < Hh) ? fmaxf(px[b][ci][hh], 0.f) : 0.f;
                    s += wk[cc][ci][kh] * val;
                }
            }
            t[b][cc][h] = s;
        }
        __syncthreads();
        for (int i = tid; i < 8 * 15 * Hh; i += 256) {
            const int h = i % Hh, cc = (i / Hh) % 15, b = i / (15 * Hh);
            float s = bk[cc];
            for (int ci = 0; ci < 15; ++ci) {
                #pragma unroll
                for (int kh = 0; kh < 3; ++kh) {
                    const int hh = h + kh - 1;
                    const float val = (hh >= 0 && hh < Hh) ? fmaxf(t[b][ci][hh], 0.f) : 0.f;
                    s += wk[cc][ci][kh] * val;
                }
            }
            r[b][cc][h] = s + px[b][cc][h];
        }
        __syncthreads();
    }

    if (tid < 16) {
        const int b = tid >> 1, o = tid & 1;
        float s = bout[o];
        for (int c = 0; c < 15; ++c)
            #pragma unroll
            for (int h = 0; h < 2; ++h)
                s += wout[o * 30 + c * 2 + h] * r[b][c][h];
        out[b * 2 + o] = s;
    }
}

// ---------------------------------------------------------------------------
extern "C" void kernel_launch(void* const* d_in, const int* in_sizes, int n_in,
                              void* d_out, int out_size, void* d_ws, size_t ws_size,
                              hipStream_t stream)
{
    const float* x = (const float*)d_in[0];
    const float* w1 = (const float*)d_in[1];  const float* b1 = (const float*)d_in[2];
    const float* g1 = (const float*)d_in[3];  const float* be1 = (const float*)d_in[4];
    const float* m1 = (const float*)d_in[5];  const float* v1 = (const float*)d_in[6];
    const float* w2 = (const float*)d_in[7];  const float* b2 = (const float*)d_in[8];
    const float* g2 = (const float*)d_in[9];  const float* be2 = (const float*)d_in[10];
    const float* m2 = (const float*)d_in[11]; const float* v2 = (const float*)d_in[12];
    const float* w3 = (const float*)d_in[13]; const float* b3 = (const float*)d_in[14];
    const float* g3 = (const float*)d_in[15]; const float* be3 = (const float*)d_in[16];
    const float* m3 = (const float*)d_in[17]; const float* v3 = (const float*)d_in[18];
    const float* w4 = (const float*)d_in[19]; const float* b4 = (const float*)d_in[20];
    const float* g4 = (const float*)d_in[21]; const float* be4 = (const float*)d_in[22];
    const float* m4 = (const float*)d_in[23]; const float* v4 = (const float*)d_in[24];
    const float* wfc = (const float*)d_in[25]; const float* bfc = (const float*)d_in[26];
    const float* wc3 = (const float*)d_in[27]; const float* bc3 = (const float*)d_in[28];
    const float* wout = (const float*)d_in[29]; const float* bout = (const float*)d_in[30];
    float* out = (float*)d_out;

    (void)in_sizes; (void)n_in; (void)out_size; (void)ws_size;

    // ---- workspace layout (floats) ----
    float* wsf = (float*)d_ws;
    float* res   = wsf;                               // [120*32]
    float* scsh  = wsf + 3840;                        // 256 floats
    float* sc2 = scsh, *sh2 = scsh + 32;
    float* sc3 = scsh + 64, *sh3 = scsh + 128;
    float* sc4 = scsh + 192, *sh4 = scsh + 224;
    unsigned short* A2  = (unsigned short*)(wsf + 4096);      // 13312 us
    unsigned short* A3  = (unsigned short*)(wsf + 10752);     // 51200 us
    unsigned short* A4  = (unsigned short*)(wsf + 36352);     // 51200 us
    unsigned short* c1o = (unsigned short*)(wsf + 61952);     // [120][50][250][16]
    unsigned short* c2o = (unsigned short*)(wsf + 12061952);  // [120][25][125][32]
    unsigned short* c3o = (unsigned short*)(wsf + 18061952);  // [120][12][62][64]
    unsigned short* c4o = (unsigned short*)(wsf + 20918912);  // [120][6][31][32]
    unsigned short* wfcT = (unsigned short*)(wsf + 21276032); // 190464 us

    // ---- prep ----
    prep_scsh<<<1, 256, 0, stream>>>(g2, be2, m2, v2, b2,
                                     g3, be3, m3, v3, b3,
                                     g4, be4, m4, v4, b4, scsh);
    prep_A<16, 32, 13><<<52, 256, 0, stream>>>(w2, A2);
    prep_A<32, 64, 25><<<200, 256, 0, stream>>>(w3, A3);
    prep_A<64, 32, 50><<<200, 256, 0, stream>>>(w4, A4);
    prep_fcw<<<744, 256, 0, stream>>>(wfc, wfcT);

    // ---- pipeline ----
    conv1_kernel<<<dim3(49, 1, 120), 256, 0, stream>>>(
        x, w1, b1, g1, be1, m1, v1, c1o);
    mfma_conv<16, 32, 50, 250, 25, 125, 13><<<dim3(8, 7, 120), 256, 0, stream>>>(
        c1o, A2, sc2, sh2, c2o);
    mfma_conv<32, 64, 25, 125, 12, 62, 25><<<dim3(4, 3, 240), 256, 0, stream>>>(
        c2o, A3, sc3, sh3, c3o);
    mfma_conv<64, 32, 12, 62, 6, 31, 50><<<dim3(2, 2, 120), 256, 0, stream>>>(
        c3o, A4, sc4, sh4, c4o);
    fc_kernel<<<dim3(120), 256, 0, stream>>>(c4o, wfcT, bfc, res);
    dpcnn_kernel<<<dim3(1), 256, 0, stream>>>(res, wc3, bc3, wout, bout, out);
}

// Round 6
// 377.409 us; speedup vs baseline: 19.3661x; 1.1980x over previous
//
#include <hip/hip_runtime.h>
#include <hip/hip_bf16.h>

#define EPS 1e-5f

typedef short bf16x8 __attribute__((ext_vector_type(8)));
typedef float f32x4  __attribute__((ext_vector_type(4)));

__device__ __forceinline__ unsigned short f2bf(float f) {
    __hip_bfloat16 h = __float2bfloat16(f);
    return *(unsigned short*)&h;
}
__device__ __forceinline__ float bf2f(unsigned short u) {
    __hip_bfloat16 h = *(__hip_bfloat16*)&u;
    return __bfloat162float(h);
}

// ---------------------------------------------------------------------------
// prep: BN scale/shift for stages 2..4 into ws (sc|sh per stage, contiguous)
// layout: sc2[32] sh2[32] sc3[64] sh3[64] sc4[32] sh4[32]  (256 floats)
// ---------------------------------------------------------------------------
__global__ void prep_scsh(
    const float* g2, const float* be2, const float* m2, const float* v2, const float* b2,
    const float* g3, const float* be3, const float* m3, const float* v3, const float* b3,
    const float* g4, const float* be4, const float* m4, const float* v4, const float* b4,
    float* base)
{
    const int t = threadIdx.x;
    if (t < 32) {
        const float sc = g2[t] / sqrtf(v2[t] + EPS);
        base[t] = sc; base[32 + t] = (b2[t] - m2[t]) * sc + be2[t];
    } else if (t < 96) {
        const int c = t - 32;
        const float sc = g3[c] / sqrtf(v3[c] + EPS);
        base[64 + c] = sc; base[128 + c] = (b3[c] - m3[c]) * sc + be3[c];
    } else if (t < 128) {
        const int c = t - 96;
        const float sc = g4[c] / sqrtf(v4[c] + EPS);
        base[192 + c] = sc; base[224 + c] = (b4[c] - m4[c]) * sc + be4[c];
    }
}

// ---------------------------------------------------------------------------
// prep: pack conv weights into per-lane MFMA A-fragments (bf16).
// ---------------------------------------------------------------------------
template <int CI, int CO, int NP>
__global__ void prep_A(const float* __restrict__ w, unsigned short* __restrict__ Apk)
{
    constexpr int COTALL = CO / 16;
    const int tot = NP * COTALL * 512;
    for (int i = blockIdx.x * 256 + threadIdx.x; i < tot; i += gridDim.x * 256) {
        const int j = i & 7, lane = (i >> 3) & 63, pc = i >> 9;
        const int p = pc / COTALL, cot = pc % COTALL;
        const int kidx = p * 32 + (lane >> 4) * 8 + j;
        const int tap = kidx / CI, ci = kidx % CI;
        const int co = cot * 16 + (lane & 15);
        const float val = (tap < 25) ? w[((size_t)co * CI + ci) * 25 + tap] : 0.f;
        Apk[i] = f2bf(val);
    }
}

// ---------------------------------------------------------------------------
// prep: permute+cast FC weight to match channels-last feats order.
// wfcT[o][j] = bf16(wfc[o][c*186 + yx])  where j = yx*32 + c
// ---------------------------------------------------------------------------
__global__ void prep_fcw(const float* __restrict__ wfc, unsigned short* __restrict__ wfcT)
{
    for (int i = blockIdx.x * 256 + threadIdx.x; i < 32 * 5952; i += gridDim.x * 256) {
        const int o = i / 5952, j = i % 5952;
        const int c = j & 31, yx = j >> 5;
        wfcT[i] = f2bf(wfc[(size_t)o * 5952 + c * 186 + yx]);
    }
}

// ---------------------------------------------------------------------------
// Stage 1 (fp32 vector): x [8,1,100,7500] -> c1o bf16 channels-last
// [120][50][250][16].  conv5x5(pad2,1->16)+BN+ReLU+pool2x2.
// ---------------------------------------------------------------------------
__global__ __launch_bounds__(256) void conv1_kernel(
    const float* __restrict__ x,
    const float* __restrict__ w, const float* __restrict__ bias,
    const float* __restrict__ g, const float* __restrict__ beta,
    const float* __restrict__ m, const float* __restrict__ v,
    unsigned short* __restrict__ out)
{
    __shared__ float wlds[16 * 25];
    __shared__ float scb[16], shb[16];
    const int n = blockIdx.z;
    for (int i = threadIdx.x; i < 16 * 25; i += 256) wlds[i] = w[i];
    if (threadIdx.x < 16) {
        const int co = threadIdx.x;
        const float sc = g[co] / sqrtf(v[co] + EPS);
        scb[co] = sc;
        shb[co] = (bias[co] - m[co]) * sc + beta[co];
    }
    __syncthreads();

    const int sp = blockIdx.x * 256 + threadIdx.x;
    if (sp >= 50 * 250) return;
    const int ph = sp / 250, pw = sp % 250;
    const int b = n / 15, c = n % 15;
    const float* xb = x + (size_t)b * 100 * 7500 + (size_t)c * 500;

    const int y0 = 2 * ph - 2, x0 = 2 * pw - 2;
    float win[6][6];
    #pragma unroll
    for (int r = 0; r < 6; ++r) {
        const int y = y0 + r;
        const bool yv = (y >= 0 && y < 100);
        const float* row = xb + y * 7500;
        #pragma unroll
        for (int cc = 0; cc < 6; ++cc) {
            const int xx = x0 + cc;
            win[r][cc] = (yv && xx >= 0 && xx < 500) ? row[xx] : 0.f;
        }
    }

    unsigned int packed[8];
    #pragma unroll
    for (int oc = 0; oc < 16; ++oc) {
        const float* wc = &wlds[oc * 25];
        float a00 = 0.f, a01 = 0.f, a10 = 0.f, a11 = 0.f;
        #pragma unroll
        for (int kh = 0; kh < 5; ++kh)
            #pragma unroll
            for (int kw = 0; kw < 5; ++kw) {
                const float wv = wc[kh * 5 + kw];
                a00 += win[kh][kw] * wv;     a01 += win[kh][kw + 1] * wv;
                a10 += win[kh + 1][kw] * wv; a11 += win[kh + 1][kw + 1] * wv;
            }
        const float sc = scb[oc], sh = shb[oc];
        a00 = fmaxf(a00 * sc + sh, 0.f); a01 = fmaxf(a01 * sc + sh, 0.f);
        a10 = fmaxf(a10 * sc + sh, 0.f); a11 = fmaxf(a11 * sc + sh, 0.f);
        const unsigned short bits = f2bf(fmaxf(fmaxf(a00, a01), fmaxf(a10, a11)));
        if (oc & 1) packed[oc >> 1] |= ((unsigned int)bits) << 16;
        else        packed[oc >> 1] = bits;
    }
    unsigned short* dst = out + (((size_t)n * 50 + ph) * 250 + pw) * 16;
    *(uint4*)(dst)     = make_uint4(packed[0], packed[1], packed[2], packed[3]);
    *(uint4*)(dst + 8) = make_uint4(packed[4], packed[5], packed[6], packed[7]);
}

// ---------------------------------------------------------------------------
// MFMA conv stage: in bf16 [N][H][W][CI] -> out bf16 [N][PH][PW][CO]
// conv5x5(pad2) + BN + ReLU + maxpool2x2, via mfma_f32_16x16x32_bf16.
// ---------------------------------------------------------------------------
template <int CI, int CO, int H, int W, int PH, int PW, int NP>
__global__ __launch_bounds__(256) void mfma_conv(
    const unsigned short* __restrict__ in,
    const unsigned short* __restrict__ Apk,
    const float* __restrict__ sc, const float* __restrict__ sh,
    unsigned short* __restrict__ outp)
{
    constexpr int TH = 8, TW = 32, ROWS = TH + 4, COLS = TW + 4;
    constexpr int CSTR = CI * 2 + 16;            // bytes per (y,x) cell
    constexpr int COTALL = CO / 16, COB = CO / 32;
    constexpr int CPC = CI / 8;                  // 16B chunks per cell
    __shared__ char smem[ROWS * COLS * CSTR];

    const int n = blockIdx.z / COB, cob = blockIdx.z % COB;
    const int ytile = blockIdx.y * TH, xtile = blockIdx.x * TW;
    const int tid = threadIdx.x;

    // ---- stage input tile (zero-padded) ----
    for (int i = tid; i < ROWS * COLS * CPC; i += 256) {
        const int cell = i / CPC, ch = i % CPC;
        const int yy = cell / COLS, xx = cell % COLS;
        const int gy = ytile - 2 + yy, gx = xtile - 2 + xx;
        uint4 val = make_uint4(0, 0, 0, 0);
        if (gy >= 0 && gy < H && gx >= 0 && gx < W)
            val = *(const uint4*)(in + ((((size_t)n * H + gy) * W + gx) * CI + ch * 8));
        *(uint4*)(smem + (size_t)(yy * COLS + xx) * CSTR + ch * 16) = val;
    }
    __syncthreads();

    const int lane = tid & 63, wav = tid >> 6;
    const int g = lane >> 4, c15 = lane & 15;
    const int laneCi = (CI == 16) ? ((g & 1) * 16) : (g * 16);
    const bool hi = (lane >= 32);

    int baddr[2][2];
    #pragma unroll
    for (int r = 0; r < 2; ++r)
        #pragma unroll
        for (int cg = 0; cg < 2; ++cg)
            baddr[r][cg] = ((wav * 2 + r) * COLS + cg * 16 + c15) * CSTR + laneCi;

    f32x4 acc[2][2][2] = {};                     // [row r][co-tile ct][colgrp cg]

    #pragma unroll
    for (int p = 0; p < NP; ++p) {
        int D;
        if (CI == 16) {
            int t0 = p * 2;     if (t0 > 24) t0 = 24;
            int t1 = p * 2 + 1; if (t1 > 24) t1 = 24;
            const int D0 = ((t0 / 5) * COLS + t0 % 5) * CSTR;
            const int D1 = ((t1 / 5) * COLS + t1 % 5) * CSTR;
            D = hi ? D1 : D0;
        } else {
            const int tap = (CI == 32) ? p : (p >> 1);
            D = ((tap / 5) * COLS + tap % 5) * CSTR + ((CI == 64) ? (p & 1) * 64 : 0);
        }
        bf16x8 a[2], b[2][2];
        #pragma unroll
        for (int ct = 0; ct < 2; ++ct)
            a[ct] = *(const bf16x8*)(Apk + ((size_t)(p * COTALL + cob * 2 + ct) * 64 + lane) * 8);
        #pragma unroll
        for (int r = 0; r < 2; ++r)
            #pragma unroll
            for (int cg = 0; cg < 2; ++cg)
                b[r][cg] = *(const bf16x8*)(smem + baddr[r][cg] + D);
        #pragma unroll
        for (int r = 0; r < 2; ++r)
            #pragma unroll
            for (int ct = 0; ct < 2; ++ct)
                #pragma unroll
                for (int cg = 0; cg < 2; ++cg)
                    acc[r][ct][cg] = __builtin_amdgcn_mfma_f32_16x16x32_bf16(
                        a[ct], b[r][cg], acc[r][ct][cg], 0, 0, 0);
    }

    // ---- epilogue: BN + ReLU + 2x2 maxpool + bf16 store (channels-last) ----
    const int py = blockIdx.y * 4 + wav;
    #pragma unroll
    for (int ct = 0; ct < 2; ++ct) {
        const int coW = cob * 32 + ct * 16;
        const float4 scv = *(const float4*)(sc + coW + g * 4);
        const float4 shv = *(const float4*)(sh + coW + g * 4);
        #pragma unroll
        for (int cg = 0; cg < 2; ++cg) {
            const int px = (xtile >> 1) + cg * 8 + (c15 >> 1);
            ushort4 st;
            #pragma unroll
            for (int reg = 0; reg < 4; ++reg) {
                const float scr = (&scv.x)[reg], shr = (&shv.x)[reg];
                const float v0 = fmaxf(acc[0][ct][cg][reg] * scr + shr, 0.f);
                const float v1 = fmaxf(acc[1][ct][cg][reg] * scr + shr, 0.f);
                float mx = fmaxf(v0, v1);
                mx = fmaxf(mx, __shfl_xor(mx, 1));
                (&st.x)[reg] = f2bf(mx);
            }
            if ((lane & 1) == 0 && py < PH && px < PW)
                *(ushort4*)(outp + (((size_t)n * PH + py) * PW + px) * CO + coW + g * 4) = st;
        }
    }
}

// ---------------------------------------------------------------------------
// FC: feats bf16 [120][5952] . wfcT bf16 [32][5952] + bfc -> res f32 [120,32]
// ---------------------------------------------------------------------------
__global__ __launch_bounds__(256) void fc_kernel(
    const unsigned short* __restrict__ feats, const unsigned short* __restrict__ wfcT,
    const float* __restrict__ bfc, float* __restrict__ res)
{
    const int n = blockIdx.x;
    const int lane = threadIdx.x & 63;
    const int wave = threadIdx.x >> 6;
    const unsigned short* f = feats + (size_t)n * 5952;
    #pragma unroll
    for (int o8 = 0; o8 < 8; ++o8) {
        const int o = wave * 8 + o8;
        const unsigned short* wr = wfcT + (size_t)o * 5952;
        float s = 0.f;
        #pragma unroll
        for (int i = 0; i < 12; ++i) {
            const int j8 = (i * 64 + lane) * 8;
            if (j8 < 5952) {
                const bf16x8 fv = *(const bf16x8*)(f + j8);
                const bf16x8 wv = *(const bf16x8*)(wr + j8);
                #pragma unroll
                for (int q = 0; q < 8; ++q)
                    s += bf2f(((const unsigned short*)&fv)[q]) *
                         bf2f(((const unsigned short*)&wv)[q]);
            }
        }
        #pragma unroll
        for (int off = 32; off > 0; off >>= 1) s += __shfl_down(s, off, 64);
        if (lane == 0) res[n * 32 + o] = s + bfc[o];
    }
}

// ---------------------------------------------------------------------------
// DPCNN head v2, one block of 512. res f32 [120,32] -> out [8,2]
// Conv inputs kept as relu'd ZERO-PADDED rows [34] -> the 45-tap inner loop is
// fully unrolled with unconditional LDS reads (batched by compiler, latency
// paid once per element). Ping-pong ar/tr; raw kept in rr for pool/residual.
// ---------------------------------------------------------------------------
__global__ __launch_bounds__(512) void dpcnn_kernel(
    const float* __restrict__ res,
    const float* __restrict__ wc3, const float* __restrict__ bc3,
    const float* __restrict__ wout, const float* __restrict__ bout,
    float* __restrict__ out)
{
    __shared__ float rr[8][15][32];   // raw r at current size
    __shared__ float ar[8][15][34];   // relu(pad(conv input)), idx h+1
    __shared__ float tr[8][15][34];   // ping-pong partner
    __shared__ float px[8][15][16];   // raw pooled
    __shared__ float wk[15][45];      // wk[cc][ci*3+kh]
    __shared__ float bk[15];

    const int tid = threadIdx.x;
    for (int i = tid; i < 15 * 45; i += 512) ((float*)wk)[i] = wc3[i];
    if (tid < 15) bk[tid] = bc3[tid];
    // init: rr raw, ar relu-pad (h34: 0..33, interior h34-1)
    for (int i = tid; i < 8 * 15 * 32; i += 512) {
        const int h = i & 31, c = (i >> 5) % 15, b = i / 480;
        const float val = res[i];
        rr[b][c][h] = val;
        ar[b][c][h + 1] = fmaxf(val, 0.f);
    }
    for (int i = tid; i < 8 * 15; i += 512) {
        const int c = i % 15, b = i / 15;
        ar[b][c][0] = 0.f; ar[b][c][33] = 0.f;
        tr[b][c][0] = 0.f; tr[b][c][33] = 0.f;
    }
    __syncthreads();

    // CONV macro: read src[b][ci][h..h+2], 45 taps unrolled.
    #define CONV45(SRC, BCH, CCH, HH)                                          \
        float s0 = bk[CCH], s1 = 0.f, s2 = 0.f;                                \
        {                                                                      \
            const float* srow = &SRC[BCH][0][HH];                              \
            const float* wrow = &wk[CCH][0];                                   \
            _Pragma("unroll")                                                  \
            for (int ci = 0; ci < 15; ++ci) {                                  \
                s0 += wrow[ci * 3 + 0] * srow[ci * 34 + 0];                    \
                s1 += wrow[ci * 3 + 1] * srow[ci * 34 + 1];                    \
                s2 += wrow[ci * 3 + 2] * srow[ci * 34 + 2];                    \
            }                                                                  \
        }                                                                      \
        const float val = s0 + s1 + s2;

    // ---- two conv passes at H=32: ar -> tr -> ar (rr raw on 2nd) ----
    {
        for (int i = tid; i < 8 * 15 * 32; i += 512) {
            const int h = i & 31, cc = (i >> 5) % 15, b = i / 480;
            CONV45(ar, b, cc, h)
            tr[b][cc][h + 1] = fmaxf(val, 0.f);
        }
        __syncthreads();
        for (int i = tid; i < 8 * 15 * 32; i += 512) {
            const int h = i & 31, cc = (i >> 5) % 15, b = i / 480;
            CONV45(tr, b, cc, h)
            rr[b][cc][h] = val;
            ar[b][cc][h + 1] = fmaxf(val, 0.f);
        }
        __syncthreads();
    }

    // ---- pyramid levels: H = 32,16,8,4 -> Hh = 16,8,4,2 ----
    for (int H = 32; H > 2; H >>= 1) {
        const int Hh = H >> 1;
        const int NE = 8 * 15 * Hh;
        // pool: rr(H) -> px raw, ar relu-pad (Hh)
        for (int i = tid; i < NE; i += 512) {
            const int h = i % Hh, cc = (i / Hh) % 15, b = i / (15 * Hh);
            const float m0 = rr[b][cc][2 * h], m1 = rr[b][cc][2 * h + 1];
            const float m2 = (2 * h + 2 < H) ? rr[b][cc][2 * h + 2] : 0.f;
            const float pv = fmaxf(fmaxf(m0, m1), m2);
            px[b][cc][h] = pv;
            ar[b][cc][h + 1] = fmaxf(pv, 0.f);
            if (h == 0) ar[b][cc][0] = 0.f;
            if (h == Hh - 1) ar[b][cc][Hh + 1] = 0.f;
        }
        __syncthreads();
        // t = conv(ar) -> tr relu-pad
        for (int i = tid; i < NE; i += 512) {
            const int h = i % Hh, cc = (i / Hh) % 15, b = i / (15 * Hh);
            CONV45(ar, b, cc, h)
            tr[b][cc][h + 1] = fmaxf(val, 0.f);
            if (h == 0) tr[b][cc][0] = 0.f;
            if (h == Hh - 1) tr[b][cc][Hh + 1] = 0.f;
        }
        __syncthreads();
        // r = conv(tr) + px -> rr raw, ar relu-pad
        for (int i = tid; i < NE; i += 512) {
            const int h = i % Hh, cc = (i / Hh) % 15, b = i / (15 * Hh);
            CONV45(tr, b, cc, h)
            const float rv = val + px[b][cc][h];
            rr[b][cc][h] = rv;
            ar[b][cc][h + 1] = fmaxf(rv, 0.f);
        }
        __syncthreads();
    }
    #undef CONV45

    // ---- final linear: k = c*2 + h over rr (H=2) ----
    if (tid < 16) {
        const int b = tid >> 1, o = tid & 1;
        float s = bout[o];
        for (int c = 0; c < 15; ++c)
            #pragma unroll
            for (int h = 0; h < 2; ++h)
                s += wout[o * 30 + c * 2 + h] * rr[b][c][h];
        out[b * 2 + o] = s;
    }
}

// ---------------------------------------------------------------------------
extern "C" void kernel_launch(void* const* d_in, const int* in_sizes, int n_in,
                              void* d_out, int out_size, void* d_ws, size_t ws_size,
                              hipStream_t stream)
{
    const float* x = (const float*)d_in[0];
    const float* w1 = (const float*)d_in[1];  const float* b1 = (const float*)d_in[2];
    const float* g1 = (const float*)d_in[3];  const float* be1 = (const float*)d_in[4];
    const float* m1 = (const float*)d_in[5];  const float* v1 = (const float*)d_in[6];
    const float* w2 = (const float*)d_in[7];  const float* b2 = (const float*)d_in[8];
    const float* g2 = (const float*)d_in[9];  const float* be2 = (const float*)d_in[10];
    const float* m2 = (const float*)d_in[11]; const float* v2 = (const float*)d_in[12];
    const float* w3 = (const float*)d_in[13]; const float* b3 = (const float*)d_in[14];
    const float* g3 = (const float*)d_in[15]; const float* be3 = (const float*)d_in[16];
    const float* m3 = (const float*)d_in[17]; const float* v3 = (const float*)d_in[18];
    const float* w4 = (const float*)d_in[19]; const float* b4 = (const float*)d_in[20];
    const float* g4 = (const float*)d_in[21]; const float* be4 = (const float*)d_in[22];
    const float* m4 = (const float*)d_in[23]; const float* v4 = (const float*)d_in[24];
    const float* wfc = (const float*)d_in[25]; const float* bfc = (const float*)d_in[26];
    const float* wc3 = (const float*)d_in[27]; const float* bc3 = (const float*)d_in[28];
    const float* wout = (const float*)d_in[29]; const float* bout = (const float*)d_in[30];
    float* out = (float*)d_out;

    (void)in_sizes; (void)n_in; (void)out_size; (void)ws_size;

    // ---- workspace layout (floats) ----
    float* wsf = (float*)d_ws;
    float* res   = wsf;                               // [120*32]
    float* scsh  = wsf + 3840;                        // 256 floats
    float* sc2 = scsh, *sh2 = scsh + 32;
    float* sc3 = scsh + 64, *sh3 = scsh + 128;
    float* sc4 = scsh + 192, *sh4 = scsh + 224;
    unsigned short* A2  = (unsigned short*)(wsf + 4096);      // 13312 us
    unsigned short* A3  = (unsigned short*)(wsf + 10752);     // 51200 us
    unsigned short* A4  = (unsigned short*)(wsf + 36352);     // 51200 us
    unsigned short* c1o = (unsigned short*)(wsf + 61952);     // [120][50][250][16]
    unsigned short* c2o = (unsigned short*)(wsf + 12061952);  // [120][25][125][32]
    unsigned short* c3o = (unsigned short*)(wsf + 18061952);  // [120][12][62][64]
    unsigned short* c4o = (unsigned short*)(wsf + 20918912);  // [120][6][31][32]
    unsigned short* wfcT = (unsigned short*)(wsf + 21276032); // 190464 us

    // ---- prep ----
    prep_scsh<<<1, 256, 0, stream>>>(g2, be2, m2, v2, b2,
                                     g3, be3, m3, v3, b3,
                                     g4, be4, m4, v4, b4, scsh);
    prep_A<16, 32, 13><<<52, 256, 0, stream>>>(w2, A2);
    prep_A<32, 64, 25><<<200, 256, 0, stream>>>(w3, A3);
    prep_A<64, 32, 50><<<200, 256, 0, stream>>>(w4, A4);
    prep_fcw<<<744, 256, 0, stream>>>(wfc, wfcT);

    // ---- pipeline ----
    conv1_kernel<<<dim3(49, 1, 120), 256, 0, stream>>>(
        x, w1, b1, g1, be1, m1, v1, c1o);
    mfma_conv<16, 32, 50, 250, 25, 125, 13><<<dim3(8, 7, 120), 256, 0, stream>>>(
        c1o, A2, sc2, sh2, c2o);
    mfma_conv<32, 64, 25, 125, 12, 62, 25><<<dim3(4, 3, 240), 256, 0, stream>>>(
        c2o, A3, sc3, sh3, c3o);
    mfma_conv<64, 32, 12, 62, 6, 31, 50><<<dim3(2, 2, 120), 256, 0, stream>>>(
        c3o, A4, sc4, sh4, c4o);
    fc_kernel<<<dim3(120), 256, 0, stream>>>(c4o, wfcT, bfc, res);
    dpcnn_kernel<<<dim3(1), 512, 0, stream>>>(res, wc3, bc3, wout, bout, out);
}

// Round 9
// 352.082 us; speedup vs baseline: 20.7592x; 1.0719x over previous
//
#include <hip/hip_runtime.h>
#include <hip/hip_bf16.h>

#define EPS 1e-5f

typedef short bf16x8 __attribute__((ext_vector_type(8)));
typedef float f32x4  __attribute__((ext_vector_type(4)));

__device__ __forceinline__ unsigned short f2bf(float f) {
    __hip_bfloat16 h = __float2bfloat16(f);
    return *(unsigned short*)&h;
}
__device__ __forceinline__ float bf2f(unsigned short u) {
    __hip_bfloat16 h = *(__hip_bfloat16*)&u;
    return __bfloat162float(h);
}

// ---------------------------------------------------------------------------
// prep: BN scale/shift for all stages into ws.
// layout: sc2[32] sh2[32] sc3[64] sh3[64] sc4[32] sh4[32] sc1[16] sh1[16]
// ---------------------------------------------------------------------------
__global__ void prep_scsh(
    const float* g1, const float* be1, const float* m1, const float* v1, const float* b1,
    const float* g2, const float* be2, const float* m2, const float* v2, const float* b2,
    const float* g3, const float* be3, const float* m3, const float* v3, const float* b3,
    const float* g4, const float* be4, const float* m4, const float* v4, const float* b4,
    float* base)
{
    const int t = threadIdx.x;
    if (t < 32) {
        const float sc = g2[t] / sqrtf(v2[t] + EPS);
        base[t] = sc; base[32 + t] = (b2[t] - m2[t]) * sc + be2[t];
    } else if (t < 96) {
        const int c = t - 32;
        const float sc = g3[c] / sqrtf(v3[c] + EPS);
        base[64 + c] = sc; base[128 + c] = (b3[c] - m3[c]) * sc + be3[c];
    } else if (t < 128) {
        const int c = t - 96;
        const float sc = g4[c] / sqrtf(v4[c] + EPS);
        base[192 + c] = sc; base[224 + c] = (b4[c] - m4[c]) * sc + be4[c];
    } else if (t < 144) {
        const int c = t - 128;
        const float sc = g1[c] / sqrtf(v1[c] + EPS);
        base[256 + c] = sc; base[272 + c] = (b1[c] - m1[c]) * sc + be1[c];
    }
}

// ---------------------------------------------------------------------------
// prep: pack conv weights into per-lane MFMA A-fragments (bf16), stages 2-4.
// ---------------------------------------------------------------------------
template <int CI, int CO, int NP>
__global__ void prep_A(const float* __restrict__ w, unsigned short* __restrict__ Apk)
{
    constexpr int COTALL = CO / 16;
    const int tot = NP * COTALL * 512;
    for (int i = blockIdx.x * 256 + threadIdx.x; i < tot; i += gridDim.x * 256) {
        const int j = i & 7, lane = (i >> 3) & 63, pc = i >> 9;
        const int p = pc / COTALL, cot = pc % COTALL;
        const int kidx = p * 32 + (lane >> 4) * 8 + j;
        const int tap = kidx / CI, ci = kidx % CI;
        const int co = cot * 16 + (lane & 15);
        const float val = (tap < 25) ? w[((size_t)co * CI + ci) * 25 + tap] : 0.f;
        Apk[i] = f2bf(val);
    }
}

// ---------------------------------------------------------------------------
// prep: A-fragment for stage 1 (CI=1): Apk1[lane*8+j] = W1[co=lane&15][tap]
// tap = (lane>>4)*8 + j, zero for tap>=25.  512 entries.
// ---------------------------------------------------------------------------
__global__ void prep_A1(const float* __restrict__ w, unsigned short* __restrict__ Apk)
{
    const int i = threadIdx.x;
    if (i < 512) {
        const int j = i & 7, lane = i >> 3;
        const int k = ((lane >> 4) & 3) * 8 + j;
        const int co = lane & 15;
        Apk[i] = f2bf((k < 25) ? w[co * 25 + k] : 0.f);
    }
}

// ---------------------------------------------------------------------------
// prep: permute+cast FC weight to match channels-last feats order.
// ---------------------------------------------------------------------------
__global__ void prep_fcw(const float* __restrict__ wfc, unsigned short* __restrict__ wfcT)
{
    for (int i = blockIdx.x * 256 + threadIdx.x; i < 32 * 5952; i += gridDim.x * 256) {
        const int o = i / 5952, j = i % 5952;
        const int c = j & 31, yx = j >> 5;
        wfcT[i] = f2bf(wfc[(size_t)o * 5952 + c * 186 + yx]);
    }
}

// ---------------------------------------------------------------------------
// Stage 1 via MFMA: x [8,1,100,7500] -> c1o bf16 [120][50][250][16].
// conv5x5(pad2,1->16)+BN+ReLU+pool2x2. All 25 taps in ONE K=32 MFMA.
// Block: 256 thr, tile = 8 conv rows x 32 conv cols -> 4x16 pooled.
// Wave w owns conv rows {2w, 2w+1}; B gathered from LDS image tile.
// ---------------------------------------------------------------------------
__global__ __launch_bounds__(256) void conv1_mfma(
    const float* __restrict__ x,
    const unsigned short* __restrict__ Apk1,
    const float* __restrict__ sc, const float* __restrict__ sh,
    unsigned short* __restrict__ out)
{
    constexpr int RSTR = 38;                     // bf16 elems per tile row
    __shared__ unsigned short tile[12 * RSTR];
    const int n = blockIdx.z;
    const int y0 = blockIdx.y * 8, x0 = blockIdx.x * 32;
    const int b = n / 15, c = n % 15;
    const float* xb = x + (size_t)b * 100 * 7500 + (size_t)c * 500;
    const int tid = threadIdx.x;

    // stage 12x36 window fp32 -> bf16 (zero-padded at chunk borders)
    for (int i = tid; i < 12 * 36; i += 256) {
        const int yy = i / 36, xx = i % 36;
        const int gy = y0 - 2 + yy, gx = x0 - 2 + xx;
        float v = 0.f;
        if (gy >= 0 && gy < 100 && gx >= 0 && gx < 500) v = xb[gy * 7500 + gx];
        tile[yy * RSTR + xx] = f2bf(v);
    }

    const int lane = tid & 63, wav = tid >> 6;
    const int g = lane >> 4, c15 = lane & 15;
    const bf16x8 a = *(const bf16x8*)(Apk1 + lane * 8);

    // per-lane tap offsets (taps k = g*8+j; mask k>=25)
    int off[8]; unsigned short msk[8];
    #pragma unroll
    for (int j = 0; j < 8; ++j) {
        int tap = g * 8 + j;
        msk[j] = (tap < 25) ? 0xFFFFu : 0u;
        if (tap > 24) tap = 24;
        off[j] = (tap / 5) * RSTR + (tap % 5);
    }
    __syncthreads();

    f32x4 acc[2][2] = {};                        // [conv row r][col group cg]
    #pragma unroll
    for (int r = 0; r < 2; ++r)
        #pragma unroll
        for (int cg = 0; cg < 2; ++cg) {
            const int base = (2 * wav + r) * RSTR + cg * 16 + c15;
            bf16x8 bfrag;
            #pragma unroll
            for (int j = 0; j < 8; ++j) {
                const unsigned short v = tile[base + off[j]] & msk[j];
                ((unsigned short*)&bfrag)[j] = (short)v;
            }
            acc[r][cg] = __builtin_amdgcn_mfma_f32_16x16x32_bf16(a, bfrag, acc[r][cg], 0, 0, 0);
        }

    // epilogue: BN + ReLU + 2x2 maxpool + bf16 channels-last store
    const int py = blockIdx.y * 4 + wav;
    const float4 scv = *(const float4*)(sc + g * 4);
    const float4 shv = *(const float4*)(sh + g * 4);
    #pragma unroll
    for (int cg = 0; cg < 2; ++cg) {
        const int px = (x0 >> 1) + cg * 8 + (c15 >> 1);
        ushort4 st;
        #pragma unroll
        for (int reg = 0; reg < 4; ++reg) {
            const float scr = (&scv.x)[reg], shr = (&shv.x)[reg];
            const float v0 = fmaxf(acc[0][cg][reg] * scr + shr, 0.f);
            const float v1 = fmaxf(acc[1][cg][reg] * scr + shr, 0.f);
            float mx = fmaxf(v0, v1);
            mx = fmaxf(mx, __shfl_xor(mx, 1));
            (&st.x)[reg] = f2bf(mx);
        }
        if ((lane & 1) == 0 && py < 50 && px < 250)
            *(ushort4*)(out + (((size_t)n * 50 + py) * 250 + px) * 16 + g * 4) = st;
    }
}

// ---------------------------------------------------------------------------
// MFMA conv stage: in bf16 [N][H][W][CI] -> out bf16 [N][PH][PW][CO]
// conv5x5(pad2) + BN + ReLU + maxpool2x2, via mfma_f32_16x16x32_bf16.
// ---------------------------------------------------------------------------
template <int CI, int CO, int H, int W, int PH, int PW, int NP>
__global__ __launch_bounds__(256) void mfma_conv(
    const unsigned short* __restrict__ in,
    const unsigned short* __restrict__ Apk,
    const float* __restrict__ sc, const float* __restrict__ sh,
    unsigned short* __restrict__ outp)
{
    constexpr int TH = 8, TW = 32, ROWS = TH + 4, COLS = TW + 4;
    constexpr int CSTR = CI * 2 + 16;            // bytes per (y,x) cell
    constexpr int COTALL = CO / 16, COB = CO / 32;
    constexpr int CPC = CI / 8;                  // 16B chunks per cell
    __shared__ char smem[ROWS * COLS * CSTR];

    const int n = blockIdx.z / COB, cob = blockIdx.z % COB;
    const int ytile = blockIdx.y * TH, xtile = blockIdx.x * TW;
    const int tid = threadIdx.x;

    for (int i = tid; i < ROWS * COLS * CPC; i += 256) {
        const int cell = i / CPC, ch = i % CPC;
        const int yy = cell / COLS, xx = cell % COLS;
        const int gy = ytile - 2 + yy, gx = xtile - 2 + xx;
        uint4 val = make_uint4(0, 0, 0, 0);
        if (gy >= 0 && gy < H && gx >= 0 && gx < W)
            val = *(const uint4*)(in + ((((size_t)n * H + gy) * W + gx) * CI + ch * 8));
        *(uint4*)(smem + (size_t)(yy * COLS + xx) * CSTR + ch * 16) = val;
    }
    __syncthreads();

    const int lane = tid & 63, wav = tid >> 6;
    const int g = lane >> 4, c15 = lane & 15;
    const int laneCi = (CI == 16) ? ((g & 1) * 16) : (g * 16);
    const bool hi = (lane >= 32);

    int baddr[2][2];
    #pragma unroll
    for (int r = 0; r < 2; ++r)
        #pragma unroll
        for (int cg = 0; cg < 2; ++cg)
            baddr[r][cg] = ((wav * 2 + r) * COLS + cg * 16 + c15) * CSTR + laneCi;

    f32x4 acc[2][2][2] = {};                     // [row r][co-tile ct][colgrp cg]

    #pragma unroll
    for (int p = 0; p < NP; ++p) {
        int D;
        if (CI == 16) {
            int t0 = p * 2;     if (t0 > 24) t0 = 24;
            int t1 = p * 2 + 1; if (t1 > 24) t1 = 24;
            const int D0 = ((t0 / 5) * COLS + t0 % 5) * CSTR;
            const int D1 = ((t1 / 5) * COLS + t1 % 5) * CSTR;
            D = hi ? D1 : D0;
        } else {
            const int tap = (CI == 32) ? p : (p >> 1);
            D = ((tap / 5) * COLS + tap % 5) * CSTR + ((CI == 64) ? (p & 1) * 64 : 0);
        }
        bf16x8 a[2], b[2][2];
        #pragma unroll
        for (int ct = 0; ct < 2; ++ct)
            a[ct] = *(const bf16x8*)(Apk + ((size_t)(p * COTALL + cob * 2 + ct) * 64 + lane) * 8);
        #pragma unroll
        for (int r = 0; r < 2; ++r)
            #pragma unroll
            for (int cg = 0; cg < 2; ++cg)
                b[r][cg] = *(const bf16x8*)(smem + baddr[r][cg] + D);
        #pragma unroll
        for (int r = 0; r < 2; ++r)
            #pragma unroll
            for (int ct = 0; ct < 2; ++ct)
                #pragma unroll
                for (int cg = 0; cg < 2; ++cg)
                    acc[r][ct][cg] = __builtin_amdgcn_mfma_f32_16x16x32_bf16(
                        a[ct], b[r][cg], acc[r][ct][cg], 0, 0, 0);
    }

    const int py = blockIdx.y * 4 + wav;
    #pragma unroll
    for (int ct = 0; ct < 2; ++ct) {
        const int coW = cob * 32 + ct * 16;
        const float4 scv = *(const float4*)(sc + coW + g * 4);
        const float4 shv = *(const float4*)(sh + coW + g * 4);
        #pragma unroll
        for (int cg = 0; cg < 2; ++cg) {
            const int px = (xtile >> 1) + cg * 8 + (c15 >> 1);
            ushort4 st;
            #pragma unroll
            for (int reg = 0; reg < 4; ++reg) {
                const float scr = (&scv.x)[reg], shr = (&shv.x)[reg];
                const float v0 = fmaxf(acc[0][ct][cg][reg] * scr + shr, 0.f);
                const float v1 = fmaxf(acc[1][ct][cg][reg] * scr + shr, 0.f);
                float mx = fmaxf(v0, v1);
                mx = fmaxf(mx, __shfl_xor(mx, 1));
                (&st.x)[reg] = f2bf(mx);
            }
            if ((lane & 1) == 0 && py < PH && px < PW)
                *(ushort4*)(outp + (((size_t)n * PH + py) * PW + px) * CO + coW + g * 4) = st;
        }
    }
}

// ---------------------------------------------------------------------------
// FC: feats bf16 [120][5952] . wfcT bf16 [32][5952] + bfc -> res f32 [120,32]
// ---------------------------------------------------------------------------
__global__ __launch_bounds__(256) void fc_kernel(
    const unsigned short* __restrict__ feats, const unsigned short* __restrict__ wfcT,
    const float* __restrict__ bfc, float* __restrict__ res)
{
    const int n = blockIdx.x;
    const int lane = threadIdx.x & 63;
    const int wave = threadIdx.x >> 6;
    const unsigned short* f = feats + (size_t)n * 5952;
    #pragma unroll
    for (int o8 = 0; o8 < 8; ++o8) {
        const int o = wave * 8 + o8;
        const unsigned short* wr = wfcT + (size_t)o * 5952;
        float s = 0.f;
        #pragma unroll
        for (int i = 0; i < 12; ++i) {
            const int j8 = (i * 64 + lane) * 8;
            if (j8 < 5952) {
                const bf16x8 fv = *(const bf16x8*)(f + j8);
                const bf16x8 wv = *(const bf16x8*)(wr + j8);
                #pragma unroll
                for (int q = 0; q < 8; ++q)
                    s += bf2f(((const unsigned short*)&fv)[q]) *
                         bf2f(((const unsigned short*)&wv)[q]);
            }
        }
        #pragma unroll
        for (int off = 32; off > 0; off >>= 1) s += __shfl_down(s, off, 64);
        if (lane == 0) res[n * 32 + o] = s + bfc[o];
    }
}

// ---------------------------------------------------------------------------
// DPCNN head v2, one block of 512. res f32 [120,32] -> out [8,2]
// ---------------------------------------------------------------------------
__global__ __launch_bounds__(512) void dpcnn_kernel(
    const float* __restrict__ res,
    const float* __restrict__ wc3, const float* __restrict__ bc3,
    const float* __restrict__ wout, const float* __restrict__ bout,
    float* __restrict__ out)
{
    __shared__ float rr[8][15][32];
    __shared__ float ar[8][15][34];
    __shared__ float tr[8][15][34];
    __shared__ float px[8][15][16];
    __shared__ float wk[15][45];
    __shared__ float bk[15];

    const int tid = threadIdx.x;
    for (int i = tid; i < 15 * 45; i += 512) ((float*)wk)[i] = wc3[i];
    if (tid < 15) bk[tid] = bc3[tid];
    for (int i = tid; i < 8 * 15 * 32; i += 512) {
        const int h = i & 31, c = (i >> 5) % 15, b = i / 480;
        const float val = res[i];
        rr[b][c][h] = val;
        ar[b][c][h + 1] = fmaxf(val, 0.f);
    }
    for (int i = tid; i < 8 * 15; i += 512) {
        const int c = i % 15, b = i / 15;
        ar[b][c][0] = 0.f; ar[b][c][33] = 0.f;
        tr[b][c][0] = 0.f; tr[b][c][33] = 0.f;
    }
    __syncthreads();

    #define CONV45(SRC, BCH, CCH, HH)                                          \
        float s0 = bk[CCH], s1 = 0.f, s2 = 0.f;                                \
        {                                                                      \
            const float* srow = &SRC[BCH][0][HH];                              \
            const float* wrow = &wk[CCH][0];                                   \
            _Pragma("unroll")                                                  \
            for (int ci = 0; ci < 15; ++ci) {                                  \
                s0 += wrow[ci * 3 + 0] * srow[ci * 34 + 0];                    \
                s1 += wrow[ci * 3 + 1] * srow[ci * 34 + 1];                    \
                s2 += wrow[ci * 3 + 2] * srow[ci * 34 + 2];                    \
            }                                                                  \
        }                                                                      \
        const float val = s0 + s1 + s2;

    {
        for (int i = tid; i < 8 * 15 * 32; i += 512) {
            const int h = i & 31, cc = (i >> 5) % 15, b = i / 480;
            CONV45(ar, b, cc, h)
            tr[b][cc][h + 1] = fmaxf(val, 0.f);
        }
        __syncthreads();
        for (int i = tid; i < 8 * 15 * 32; i += 512) {
            const int h = i & 31, cc = (i >> 5) % 15, b = i / 480;
            CONV45(tr, b, cc, h)
            rr[b][cc][h] = val;
            ar[b][cc][h + 1] = fmaxf(val, 0.f);
        }
        __syncthreads();
    }

    for (int H = 32; H > 2; H >>= 1) {
        const int Hh = H >> 1;
        const int NE = 8 * 15 * Hh;
        for (int i = tid; i < NE; i += 512) {
            const int h = i % Hh, cc = (i / Hh) % 15, b = i / (15 * Hh);
            const float m0 = rr[b][cc][2 * h], m1 = rr[b][cc][2 * h + 1];
            const float m2 = (2 * h + 2 < H) ? rr[b][cc][2 * h + 2] : 0.f;
            const float pv = fmaxf(fmaxf(m0, m1), m2);
            px[b][cc][h] = pv;
            ar[b][cc][h + 1] = fmaxf(pv, 0.f);
            if (h == 0) ar[b][cc][0] = 0.f;
            if (h == Hh - 1) ar[b][cc][Hh + 1] = 0.f;
        }
        __syncthreads();
        for (int i = tid; i < NE; i += 512) {
            const int h = i % Hh, cc = (i / Hh) % 15, b = i / (15 * Hh);
            CONV45(ar, b, cc, h)
            tr[b][cc][h + 1] = fmaxf(val, 0.f);
            if (h == 0) tr[b][cc][0] = 0.f;
            if (h == Hh - 1) tr[b][cc][Hh + 1] = 0.f;
        }
        __syncthreads();
        for (int i = tid; i < NE; i += 512) {
            const int h = i % Hh, cc = (i / Hh) % 15, b = i / (15 * Hh);
            CONV45(tr, b, cc, h)
            const float rv = val + px[b][cc][h];
            rr[b][cc][h] = rv;
            ar[b][cc][h + 1] = fmaxf(rv, 0.f);
        }
        __syncthreads();
    }
    #undef CONV45

    if (tid < 16) {
        const int b = tid >> 1, o = tid & 1;
        float s = bout[o];
        for (int c = 0; c < 15; ++c)
            #pragma unroll
            for (int h = 0; h < 2; ++h)
                s += wout[o * 30 + c * 2 + h] * rr[b][c][h];
        out[b * 2 + o] = s;
    }
}

// ---------------------------------------------------------------------------
extern "C" void kernel_launch(void* const* d_in, const int* in_sizes, int n_in,
                              void* d_out, int out_size, void* d_ws, size_t ws_size,
                              hipStream_t stream)
{
    const float* x = (const float*)d_in[0];
    const float* w1 = (const float*)d_in[1];  const float* b1 = (const float*)d_in[2];
    const float* g1 = (const float*)d_in[3];  const float* be1 = (const float*)d_in[4];
    const float* m1 = (const float*)d_in[5];  const float* v1 = (const float*)d_in[6];
    const float* w2 = (const float*)d_in[7];  const float* b2 = (const float*)d_in[8];
    const float* g2 = (const float*)d_in[9];  const float* be2 = (const float*)d_in[10];
    const float* m2 = (const float*)d_in[11]; const float* v2 = (const float*)d_in[12];
    const float* w3 = (const float*)d_in[13]; const float* b3 = (const float*)d_in[14];
    const float* g3 = (const float*)d_in[15]; const float* be3 = (const float*)d_in[16];
    const float* m3 = (const float*)d_in[17]; const float* v3 = (const float*)d_in[18];
    const float* w4 = (const float*)d_in[19]; const float* b4 = (const float*)d_in[20];
    const float* g4 = (const float*)d_in[21]; const float* be4 = (const float*)d_in[22];
    const float* m4 = (const float*)d_in[23]; const float* v4 = (const float*)d_in[24];
    const float* wfc = (const float*)d_in[25]; const float* bfc = (const float*)d_in[26];
    const float* wc3 = (const float*)d_in[27]; const float* bc3 = (const float*)d_in[28];
    const float* wout = (const float*)d_in[29]; const float* bout = (const float*)d_in[30];
    float* out = (float*)d_out;

    (void)in_sizes; (void)n_in; (void)out_size; (void)ws_size;

    // ---- workspace layout (float offsets) ----
    float* wsf = (float*)d_ws;
    float* res   = wsf;                               // [120*32]         0..3840
    float* scsh  = wsf + 3840;                        // 288 floats       3840..4128
    float* sc2 = scsh, *sh2 = scsh + 32;
    float* sc3 = scsh + 64, *sh3 = scsh + 128;
    float* sc4 = scsh + 192, *sh4 = scsh + 224;
    float* sc1 = scsh + 256, *sh1 = scsh + 272;
    unsigned short* A1  = (unsigned short*)(wsf + 4160);      // 512 sh    -> 4416
    unsigned short* A2  = (unsigned short*)(wsf + 4416);      // 13312 sh  -> 11072
    unsigned short* A3  = (unsigned short*)(wsf + 11072);     // 51200 sh  -> 36672
    unsigned short* A4  = (unsigned short*)(wsf + 36672);     // 51200 sh  -> 62272
    unsigned short* c1o = (unsigned short*)(wsf + 62272);     // [120][50][250][16]
    unsigned short* c2o = (unsigned short*)(wsf + 12062272);  // [120][25][125][32]
    unsigned short* c3o = (unsigned short*)(wsf + 18062272);  // [120][12][62][64]
    unsigned short* c4o = (unsigned short*)(wsf + 20919232);  // [120][6][31][32]
    unsigned short* wfcT = (unsigned short*)(wsf + 21276352); // 190464 sh

    // ---- prep ----
    prep_scsh<<<1, 256, 0, stream>>>(g1, be1, m1, v1, b1,
                                     g2, be2, m2, v2, b2,
                                     g3, be3, m3, v3, b3,
                                     g4, be4, m4, v4, b4, scsh);
    prep_A1<<<1, 512, 0, stream>>>(w1, A1);
    prep_A<16, 32, 13><<<52, 256, 0, stream>>>(w2, A2);
    prep_A<32, 64, 25><<<200, 256, 0, stream>>>(w3, A3);
    prep_A<64, 32, 50><<<200, 256, 0, stream>>>(w4, A4);
    prep_fcw<<<744, 256, 0, stream>>>(wfc, wfcT);

    // ---- pipeline ----
    conv1_mfma<<<dim3(16, 13, 120), 256, 0, stream>>>(x, A1, sc1, sh1, c1o);
    mfma_conv<16, 32, 50, 250, 25, 125, 13><<<dim3(8, 7, 120), 256, 0, stream>>>(
        c1o, A2, sc2, sh2, c2o);
    mfma_conv<32, 64, 25, 125, 12, 62, 25><<<dim3(4, 3, 240), 256, 0, stream>>>(
        c2o, A3, sc3, sh3, c3o);
    mfma_conv<64, 32, 12, 62, 6, 31, 50><<<dim3(2, 2, 120), 256, 0, stream>>>(
        c3o, A4, sc4, sh4, c4o);
    fc_kernel<<<dim3(120), 256, 0, stream>>>(c4o, wfcT, bfc, res);
    dpcnn_kernel<<<dim3(1), 512, 0, stream>>>(res, wc3, bc3, wout, bout, out);
}

// Round 11
// 322.758 us; speedup vs baseline: 22.6452x; 1.0909x over previous
//
#include <hip/hip_runtime.h>
#include <hip/hip_bf16.h>

#define EPS 1e-5f

typedef short bf16x8 __attribute__((ext_vector_type(8)));
typedef float f32x4  __attribute__((ext_vector_type(4)));

__device__ __forceinline__ unsigned short f2bf(float f) {
    __hip_bfloat16 h = __float2bfloat16(f);
    return *(unsigned short*)&h;
}
__device__ __forceinline__ float bf2f(unsigned short u) {
    __hip_bfloat16 h = *(__hip_bfloat16*)&u;
    return __bfloat162float(h);
}

// ---------------------------------------------------------------------------
// prep_all: ALL weight prep in ONE kernel (was 6 launches).
// Segments (flat index): [0,144) scsh | [144,656) A1 | A2 | A3 | A4 | wfcT
// ---------------------------------------------------------------------------
__device__ __forceinline__ void packA(const float* __restrict__ w,
                                      unsigned short* __restrict__ Apk,
                                      int i, int CI, int COTALL)
{
    const int j = i & 7, lane = (i >> 3) & 63, pc = i >> 9;
    const int p = pc / COTALL, cot = pc % COTALL;
    const int kidx = p * 32 + (lane >> 4) * 8 + j;
    const int tap = kidx / CI, ci = kidx % CI;
    const int co = cot * 16 + (lane & 15);
    Apk[i] = f2bf((tap < 25) ? w[((size_t)co * CI + ci) * 25 + tap] : 0.f);
}

__global__ void prep_all(
    const float* w1, const float* w2, const float* w3, const float* w4,
    const float* wfc,
    const float* g1, const float* be1, const float* m1, const float* v1, const float* b1,
    const float* g2, const float* be2, const float* m2, const float* v2, const float* b2,
    const float* g3, const float* be3, const float* m3, const float* v3, const float* b3,
    const float* g4, const float* be4, const float* m4, const float* v4, const float* b4,
    float* scsh, unsigned short* A1, unsigned short* A2, unsigned short* A3,
    unsigned short* A4, unsigned short* wfcT)
{
    constexpr int S0 = 144, S1 = S0 + 512, S2 = S1 + 13312;
    constexpr int S3 = S2 + 51200, S4 = S3 + 51200, S5 = S4 + 190464;
    const int idx = blockIdx.x * 256 + threadIdx.x;
    if (idx < S0) {
        const int t = idx;
        if (t < 32) {
            const float sc = g2[t] / sqrtf(v2[t] + EPS);
            scsh[t] = sc; scsh[32 + t] = (b2[t] - m2[t]) * sc + be2[t];
        } else if (t < 96) {
            const int c = t - 32;
            const float sc = g3[c] / sqrtf(v3[c] + EPS);
            scsh[64 + c] = sc; scsh[128 + c] = (b3[c] - m3[c]) * sc + be3[c];
        } else if (t < 128) {
            const int c = t - 96;
            const float sc = g4[c] / sqrtf(v4[c] + EPS);
            scsh[192 + c] = sc; scsh[224 + c] = (b4[c] - m4[c]) * sc + be4[c];
        } else {
            const int c = t - 128;
            const float sc = g1[c] / sqrtf(v1[c] + EPS);
            scsh[256 + c] = sc; scsh[272 + c] = (b1[c] - m1[c]) * sc + be1[c];
        }
    } else if (idx < S1) {
        const int i = idx - S0;
        const int j = i & 7, lane = i >> 3;
        const int k = ((lane >> 4) & 3) * 8 + j;
        A1[i] = f2bf((k < 25) ? w1[(lane & 15) * 25 + k] : 0.f);
    } else if (idx < S2) {
        packA(w2, A2, idx - S1, 16, 2);
    } else if (idx < S3) {
        packA(w3, A3, idx - S2, 32, 4);
    } else if (idx < S4) {
        packA(w4, A4, idx - S3, 64, 2);
    } else if (idx < S5) {
        const int i = idx - S4;
        const int o = i / 5952, j = i % 5952;
        const int c = j & 31, yx = j >> 5;
        wfcT[i] = f2bf(wfc[(size_t)o * 5952 + c * 186 + yx]);
    }
}

// ---------------------------------------------------------------------------
// Stage 1 via MFMA: x [8,1,100,7500] -> c1o bf16 [120][50][250][16].
// TW=64 (8 MFMAs/wave), no B-mask (A already zero for taps>=25).
// ---------------------------------------------------------------------------
__global__ __launch_bounds__(256) void conv1_mfma(
    const float* __restrict__ x,
    const unsigned short* __restrict__ Apk1,
    const float* __restrict__ sc, const float* __restrict__ sh,
    unsigned short* __restrict__ out)
{
    constexpr int RSTR = 70;                     // bf16 elems per tile row
    __shared__ unsigned short tile[12 * RSTR];
    const int n = blockIdx.z;
    const int y0 = blockIdx.y * 8, x0 = blockIdx.x * 64;
    const int b = n / 15, c = n % 15;
    const float* xb = x + (size_t)b * 100 * 7500 + (size_t)c * 500;
    const int tid = threadIdx.x;

    // stage 12x68 window fp32 -> bf16 (zero-padded at chunk borders)
    for (int i = tid; i < 12 * 68; i += 256) {
        const int yy = i / 68, xx = i % 68;
        const int gy = y0 - 2 + yy, gx = x0 - 2 + xx;
        float v = 0.f;
        if (gy >= 0 && gy < 100 && gx >= 0 && gx < 500) v = xb[gy * 7500 + gx];
        tile[yy * RSTR + xx] = f2bf(v);
    }

    const int lane = tid & 63, wav = tid >> 6;
    const int g = lane >> 4, c15 = lane & 15;
    const bf16x8 a = *(const bf16x8*)(Apk1 + lane * 8);

    // per-lane tap offsets (taps k = g*8+j; clamp k>=25 -> 24, A is zero there)
    int off[8];
    #pragma unroll
    for (int j = 0; j < 8; ++j) {
        int tap = g * 8 + j;
        if (tap > 24) tap = 24;
        off[j] = (tap / 5) * RSTR + (tap % 5);
    }
    __syncthreads();

    f32x4 acc[2][4] = {};                        // [conv row r][col group cg]
    #pragma unroll
    for (int r = 0; r < 2; ++r)
        #pragma unroll
        for (int cg = 0; cg < 4; ++cg) {
            const int base = (2 * wav + r) * RSTR + cg * 16 + c15;
            bf16x8 bfrag;
            #pragma unroll
            for (int j = 0; j < 8; ++j)
                ((unsigned short*)&bfrag)[j] = (short)tile[base + off[j]];
            acc[r][cg] = __builtin_amdgcn_mfma_f32_16x16x32_bf16(a, bfrag, acc[r][cg], 0, 0, 0);
        }

    // epilogue: BN + ReLU + 2x2 maxpool + bf16 channels-last store
    const int py = blockIdx.y * 4 + wav;
    const float4 scv = *(const float4*)(sc + g * 4);
    const float4 shv = *(const float4*)(sh + g * 4);
    #pragma unroll
    for (int cg = 0; cg < 4; ++cg) {
        const int px = (x0 >> 1) + cg * 8 + (c15 >> 1);
        ushort4 st;
        #pragma unroll
        for (int reg = 0; reg < 4; ++reg) {
            const float scr = (&scv.x)[reg], shr = (&shv.x)[reg];
            const float v0 = fmaxf(acc[0][cg][reg] * scr + shr, 0.f);
            const float v1 = fmaxf(acc[1][cg][reg] * scr + shr, 0.f);
            float mx = fmaxf(v0, v1);
            mx = fmaxf(mx, __shfl_xor(mx, 1));
            (&st.x)[reg] = f2bf(mx);
        }
        if ((lane & 1) == 0 && py < 50 && px < 250)
            *(ushort4*)(out + (((size_t)n * 50 + py) * 250 + px) * 16 + g * 4) = st;
    }
}

// ---------------------------------------------------------------------------
// MFMA conv stage v2: channel-plane LDS layout.
// smem = CPC planes of [ROWS*COLS] 16B cells; plane stride padded so both
// staging writes and ds_read_b128 reads are bank-conflict-free.
// Tap offsets are compile-time immediates for CI=32/64 (zero addr VALU).
// NCT = co-tiles per block (16 co each).
// ---------------------------------------------------------------------------
template <int CI, int CO, int H, int W, int PH, int PW, int NP, int NCT>
__global__ __launch_bounds__(256) void mfma_conv(
    const unsigned short* __restrict__ in,
    const unsigned short* __restrict__ Apk,
    const float* __restrict__ sc, const float* __restrict__ sh,
    unsigned short* __restrict__ outp)
{
    constexpr int TH = 8, TW = 32, ROWS = TH + 4, COLS = TW + 4;
    constexpr int CPC = CI / 8;                    // planes (8 ci each)
    constexpr int PLANESZ = ROWS * COLS * 16;      // bytes per plane
    constexpr int PPAD = (CPC == 2) ? 64 : (CPC == 4 ? 32 : 16);
    constexpr int PSTR = PLANESZ + PPAD;
    constexpr int COTALL = CO / 16;
    constexpr int COB = CO / (16 * NCT);
    __shared__ char smem[CPC * PSTR];

    const int n = blockIdx.z / COB, cob = blockIdx.z % COB;
    const int ytile = blockIdx.y * TH, xtile = blockIdx.x * TW;
    const int tid = threadIdx.x;

    // ---- stage input tile (zero-padded), plane layout ----
    for (int i = tid; i < ROWS * COLS * CPC; i += 256) {
        const int cell = i / CPC, ch = i % CPC;
        const int yy = cell / COLS, xx = cell % COLS;
        const int gy = ytile - 2 + yy, gx = xtile - 2 + xx;
        uint4 val = make_uint4(0, 0, 0, 0);
        if (gy >= 0 && gy < H && gx >= 0 && gx < W)
            val = *(const uint4*)(in + ((((size_t)n * H + gy) * W + gx) * CI + ch * 8));
        *(uint4*)(smem + ch * PSTR + cell * 16) = val;
    }
    __syncthreads();

    const int lane = tid & 63, wav = tid >> 6;
    const int g = lane >> 4, c15 = lane & 15;
    const bool hi = (lane >= 32);
    // plane: CI=16 -> g&1 (hi selects tap); CI=32 -> g; CI=64 -> g (+4 via imm)
    const int plane = (CI == 16) ? (g & 1) : g;
    const char* bbase = smem + plane * PSTR + ((wav * 2) * COLS + c15) * 16;

    f32x4 acc[2][NCT][2] = {};                     // [row r][co-tile ct][colgrp cg]

    #pragma unroll
    for (int p = 0; p < NP; ++p) {
        int Dv = 0;
        if (CI == 16) {
            int t0 = p * 2;     if (t0 > 24) t0 = 24;
            int t1 = p * 2 + 1; if (t1 > 24) t1 = 24;
            const int D0 = ((t0 / 5) * COLS + t0 % 5) * 16;
            const int D1 = ((t1 / 5) * COLS + t1 % 5) * 16;
            Dv = hi ? D1 : D0;
        }
        const int tap = (CI == 32) ? p : ((CI == 64) ? (p >> 1) : 0);
        const int pimm = (CI == 64) ? (p & 1) * 4 * PSTR : 0;

        bf16x8 a[NCT], b[2][2];
        #pragma unroll
        for (int ct = 0; ct < NCT; ++ct)
            a[ct] = *(const bf16x8*)(Apk +
                ((size_t)(p * COTALL + cob * NCT + ct) * 64 + lane) * 8);
        #pragma unroll
        for (int r = 0; r < 2; ++r)
            #pragma unroll
            for (int cg = 0; cg < 2; ++cg) {
                const int imm = (CI == 16)
                    ? (r * COLS + cg * 16) * 16
                    : (((r + tap / 5) * COLS + cg * 16 + tap % 5) * 16 + pimm);
                b[r][cg] = *(const bf16x8*)(bbase + Dv + imm);
            }
        #pragma unroll
        for (int r = 0; r < 2; ++r)
            #pragma unroll
            for (int ct = 0; ct < NCT; ++ct)
                #pragma unroll
                for (int cg = 0; cg < 2; ++cg)
                    acc[r][ct][cg] = __builtin_amdgcn_mfma_f32_16x16x32_bf16(
                        a[ct], b[r][cg], acc[r][ct][cg], 0, 0, 0);
    }

    // ---- epilogue: BN + ReLU + 2x2 maxpool + bf16 channels-last store ----
    const int py = blockIdx.y * 4 + wav;
    #pragma unroll
    for (int ct = 0; ct < NCT; ++ct) {
        const int coW = (cob * NCT + ct) * 16;
        const float4 scv = *(const float4*)(sc + coW + g * 4);
        const float4 shv = *(const float4*)(sh + coW + g * 4);
        #pragma unroll
        for (int cg = 0; cg < 2; ++cg) {
            const int px = (xtile >> 1) + cg * 8 + (c15 >> 1);
            ushort4 st;
            #pragma unroll
            for (int reg = 0; reg < 4; ++reg) {
                const float scr = (&scv.x)[reg], shr = (&shv.x)[reg];
                const float v0 = fmaxf(acc[0][ct][cg][reg] * scr + shr, 0.f);
                const float v1 = fmaxf(acc[1][ct][cg][reg] * scr + shr, 0.f);
                float mx = fmaxf(v0, v1);
                mx = fmaxf(mx, __shfl_xor(mx, 1));
                (&st.x)[reg] = f2bf(mx);
            }
            if ((lane & 1) == 0 && py < PH && px < PW)
                *(ushort4*)(outp + (((size_t)n * PH + py) * PW + px) * CO + coW + g * 4) = st;
        }
    }
}

// ---------------------------------------------------------------------------
// FC: feats bf16 [120][5952] . wfcT bf16 [32][5952] + bfc -> res f32 [120,32]
// ---------------------------------------------------------------------------
__global__ __launch_bounds__(256) void fc_kernel(
    const unsigned short* __restrict__ feats, const unsigned short* __restrict__ wfcT,
    const float* __restrict__ bfc, float* __restrict__ res)
{
    const int n = blockIdx.x;
    const int lane = threadIdx.x & 63;
    const int wave = threadIdx.x >> 6;
    const unsigned short* f = feats + (size_t)n * 5952;
    #pragma unroll
    for (int o8 = 0; o8 < 8; ++o8) {
        const int o = wave * 8 + o8;
        const unsigned short* wr = wfcT + (size_t)o * 5952;
        float s = 0.f;
        #pragma unroll
        for (int i = 0; i < 12; ++i) {
            const int j8 = (i * 64 + lane) * 8;
            if (j8 < 5952) {
                const bf16x8 fv = *(const bf16x8*)(f + j8);
                const bf16x8 wv = *(const bf16x8*)(wr + j8);
                #pragma unroll
                for (int q = 0; q < 8; ++q)
                    s += bf2f(((const unsigned short*)&fv)[q]) *
                         bf2f(((const unsigned short*)&wv)[q]);
            }
        }
        #pragma unroll
        for (int off = 32; off > 0; off >>= 1) s += __shfl_down(s, off, 64);
        if (lane == 0) res[n * 32 + o] = s + bfc[o];
    }
}

// ---------------------------------------------------------------------------
// DPCNN head, one block of 512. res f32 [120,32] -> out [8,2]
// ---------------------------------------------------------------------------
__global__ __launch_bounds__(512) void dpcnn_kernel(
    const float* __restrict__ res,
    const float* __restrict__ wc3, const float* __restrict__ bc3,
    const float* __restrict__ wout, const float* __restrict__ bout,
    float* __restrict__ out)
{
    __shared__ float rr[8][15][32];
    __shared__ float ar[8][15][34];
    __shared__ float tr[8][15][34];
    __shared__ float px[8][15][16];
    __shared__ float wk[15][45];
    __shared__ float bk[15];

    const int tid = threadIdx.x;
    for (int i = tid; i < 15 * 45; i += 512) ((float*)wk)[i] = wc3[i];
    if (tid < 15) bk[tid] = bc3[tid];
    for (int i = tid; i < 8 * 15 * 32; i += 512) {
        const int h = i & 31, c = (i >> 5) % 15, b = i / 480;
        const float val = res[i];
        rr[b][c][h] = val;
        ar[b][c][h + 1] = fmaxf(val, 0.f);
    }
    for (int i = tid; i < 8 * 15; i += 512) {
        const int c = i % 15, b = i / 15;
        ar[b][c][0] = 0.f; ar[b][c][33] = 0.f;
        tr[b][c][0] = 0.f; tr[b][c][33] = 0.f;
    }
    __syncthreads();

    #define CONV45(SRC, BCH, CCH, HH)                                          \
        float s0 = bk[CCH], s1 = 0.f, s2 = 0.f;                                \
        {                                                                      \
            const float* srow = &SRC[BCH][0][HH];                              \
            const float* wrow = &wk[CCH][0];                                   \
            _Pragma("unroll")                                                  \
            for (int ci = 0; ci < 15; ++ci) {                                  \
                s0 += wrow[ci * 3 + 0] * srow[ci * 34 + 0];                    \
                s1 += wrow[ci * 3 + 1] * srow[ci * 34 + 1];                    \
                s2 += wrow[ci * 3 + 2] * srow[ci * 34 + 2];                    \
            }                                                                  \
        }                                                                      \
        const float val = s0 + s1 + s2;

    {
        for (int i = tid; i < 8 * 15 * 32; i += 512) {
            const int h = i & 31, cc = (i >> 5) % 15, b = i / 480;
            CONV45(ar, b, cc, h)
            tr[b][cc][h + 1] = fmaxf(val, 0.f);
        }
        __syncthreads();
        for (int i = tid; i < 8 * 15 * 32; i += 512) {
            const int h = i & 31, cc = (i >> 5) % 15, b = i / 480;
            CONV45(tr, b, cc, h)
            rr[b][cc][h] = val;
            ar[b][cc][h + 1] = fmaxf(val, 0.f);
        }
        __syncthreads();
    }

    for (int H = 32; H > 2; H >>= 1) {
        const int Hh = H >> 1;
        const int NE = 8 * 15 * Hh;
        for (int i = tid; i < NE; i += 512) {
            const int h = i % Hh, cc = (i / Hh) % 15, b = i / (15 * Hh);
            const float m0 = rr[b][cc][2 * h], m1 = rr[b][cc][2 * h + 1];
            const float m2 = (2 * h + 2 < H) ? rr[b][cc][2 * h + 2] : 0.f;
            const float pv = fmaxf(fmaxf(m0, m1), m2);
            px[b][cc][h] = pv;
            ar[b][cc][h + 1] = fmaxf(pv, 0.f);
            if (h == 0) ar[b][cc][0] = 0.f;
            if (h == Hh - 1) ar[b][cc][Hh + 1] = 0.f;
        }
        __syncthreads();
        for (int i = tid; i < NE; i += 512) {
            const int h = i % Hh, cc = (i / Hh) % 15, b = i / (15 * Hh);
            CONV45(ar, b, cc, h)
            tr[b][cc][h + 1] = fmaxf(val, 0.f);
            if (h == 0) tr[b][cc][0] = 0.f;
            if (h == Hh - 1) tr[b][cc][Hh + 1] = 0.f;
        }
        __syncthreads();
        for (int i = tid; i < NE; i += 512) {
            const int h = i % Hh, cc = (i / Hh) % 15, b = i / (15 * Hh);
            CONV45(tr, b, cc, h)
            const float rv = val + px[b][cc][h];
            rr[b][cc][h] = rv;
            ar[b][cc][h + 1] = fmaxf(rv, 0.f);
        }
        __syncthreads();
    }
    #undef CONV45

    if (tid < 16) {
        const int b = tid >> 1, o = tid & 1;
        float s = bout[o];
        for (int c = 0; c < 15; ++c)
            #pragma unroll
            for (int h = 0; h < 2; ++h)
                s += wout[o * 30 + c * 2 + h] * rr[b][c][h];
        out[b * 2 + o] = s;
    }
}

// ---------------------------------------------------------------------------
extern "C" void kernel_launch(void* const* d_in, const int* in_sizes, int n_in,
                              void* d_out, int out_size, void* d_ws, size_t ws_size,
                              hipStream_t stream)
{
    const float* x = (const float*)d_in[0];
    const float* w1 = (const float*)d_in[1];  const float* b1 = (const float*)d_in[2];
    const float* g1 = (const float*)d_in[3];  const float* be1 = (const float*)d_in[4];
    const float* m1 = (const float*)d_in[5];  const float* v1 = (const float*)d_in[6];
    const float* w2 = (const float*)d_in[7];  const float* b2 = (const float*)d_in[8];
    const float* g2 = (const float*)d_in[9];  const float* be2 = (const float*)d_in[10];
    const float* m2 = (const float*)d_in[11]; const float* v2 = (const float*)d_in[12];
    const float* w3 = (const float*)d_in[13]; const float* b3 = (const float*)d_in[14];
    const float* g3 = (const float*)d_in[15]; const float* be3 = (const float*)d_in[16];
    const float* m3 = (const float*)d_in[17]; const float* v3 = (const float*)d_in[18];
    const float* w4 = (const float*)d_in[19]; const float* b4 = (const float*)d_in[20];
    const float* g4 = (const float*)d_in[21]; const float* be4 = (const float*)d_in[22];
    const float* m4 = (const float*)d_in[23]; const float* v4 = (const float*)d_in[24];
    const float* wfc = (const float*)d_in[25]; const float* bfc = (const float*)d_in[26];
    const float* wc3 = (const float*)d_in[27]; const float* bc3 = (const float*)d_in[28];
    const float* wout = (const float*)d_in[29]; const float* bout = (const float*)d_in[30];
    float* out = (float*)d_out;

    (void)in_sizes; (void)n_in; (void)out_size; (void)ws_size;

    // ---- workspace layout (float offsets) ----
    float* wsf = (float*)d_ws;
    float* res   = wsf;                               // [120*32]
    float* scsh  = wsf + 3840;                        // 288 floats
    float* sc2 = scsh, *sh2 = scsh + 32;
    float* sc3 = scsh + 64, *sh3 = scsh + 128;
    float* sc4 = scsh + 192, *sh4 = scsh + 224;
    float* sc1 = scsh + 256, *sh1 = scsh + 272;
    unsigned short* A1  = (unsigned short*)(wsf + 4160);      // 512 sh
    unsigned short* A2  = (unsigned short*)(wsf + 4416);      // 13312 sh
    unsigned short* A3  = (unsigned short*)(wsf + 11072);     // 51200 sh
    unsigned short* A4  = (unsigned short*)(wsf + 36672);     // 51200 sh
    unsigned short* c1o = (unsigned short*)(wsf + 62272);     // [120][50][250][16]
    unsigned short* c2o = (unsigned short*)(wsf + 12062272);  // [120][25][125][32]
    unsigned short* c3o = (unsigned short*)(wsf + 18062272);  // [120][12][62][64]
    unsigned short* c4o = (unsigned short*)(wsf + 20919232);  // [120][6][31][32]
    unsigned short* wfcT = (unsigned short*)(wsf + 21276352); // 190464 sh

    // ---- single merged prep (306832 elems -> 1199 blocks) ----
    prep_all<<<1199, 256, 0, stream>>>(
        w1, w2, w3, w4, wfc,
        g1, be1, m1, v1, b1, g2, be2, m2, v2, b2,
        g3, be3, m3, v3, b3, g4, be4, m4, v4, b4,
        scsh, A1, A2, A3, A4, wfcT);

    // ---- pipeline ----
    conv1_mfma<<<dim3(8, 13, 120), 256, 0, stream>>>(x, A1, sc1, sh1, c1o);
    mfma_conv<16, 32, 50, 250, 25, 125, 13, 2><<<dim3(8, 7, 120), 256, 0, stream>>>(
        c1o, A2, sc2, sh2, c2o);
    mfma_conv<32, 64, 25, 125, 12, 62, 25, 4><<<dim3(4, 3, 120), 256, 0, stream>>>(
        c2o, A3, sc3, sh3, c3o);
    mfma_conv<64, 32, 12, 62, 6, 31, 50, 2><<<dim3(2, 2, 120), 256, 0, stream>>>(
        c3o, A4, sc4, sh4, c4o);
    fc_kernel<<<dim3(120), 256, 0, stream>>>(c4o, wfcT, bfc, res);
    dpcnn_kernel<<<dim3(1), 512, 0, stream>>>(res, wc3, bc3, wout, bout, out);
}

// Round 12
// 306.685 us; speedup vs baseline: 23.8320x; 1.0524x over previous
//
#include <hip/hip_runtime.h>
#include <hip/hip_bf16.h>

#define EPS 1e-5f

typedef short bf16x8 __attribute__((ext_vector_type(8)));
typedef float f32x4  __attribute__((ext_vector_type(4)));

__device__ __forceinline__ unsigned short f2bf(float f) {
    __hip_bfloat16 h = __float2bfloat16(f);
    return *(unsigned short*)&h;
}
__device__ __forceinline__ float bf2f(unsigned short u) {
    __hip_bfloat16 h = *(__hip_bfloat16*)&u;
    return __bfloat162float(h);
}

// ---------------------------------------------------------------------------
// prep_all: ALL weight prep in ONE kernel.
// Segments: [0,144) scsh | A1(512) | A2(13312) | A3(51200) | A4(53248) | wfcT
// A4 uses PAIRED packing for the fused stage4 kernel: p = qt*13+tp;
// lane-group g: tap = tp*2 + (g>>1), ci = qt*16 + (g&1)*8 + j.
// ---------------------------------------------------------------------------
__device__ __forceinline__ void packA(const float* __restrict__ w,
                                      unsigned short* __restrict__ Apk,
                                      int i, int CI, int COTALL)
{
    const int j = i & 7, lane = (i >> 3) & 63, pc = i >> 9;
    const int p = pc / COTALL, cot = pc % COTALL;
    const int kidx = p * 32 + (lane >> 4) * 8 + j;
    const int tap = kidx / CI, ci = kidx % CI;
    const int co = cot * 16 + (lane & 15);
    Apk[i] = f2bf((tap < 25) ? w[((size_t)co * CI + ci) * 25 + tap] : 0.f);
}

__global__ void prep_all(
    const float* w1, const float* w2, const float* w3, const float* w4,
    const float* wfc,
    const float* g1, const float* be1, const float* m1, const float* v1, const float* b1,
    const float* g2, const float* be2, const float* m2, const float* v2, const float* b2,
    const float* g3, const float* be3, const float* m3, const float* v3, const float* b3,
    const float* g4, const float* be4, const float* m4, const float* v4, const float* b4,
    float* scsh, unsigned short* A1, unsigned short* A2, unsigned short* A3,
    unsigned short* A4, unsigned short* wfcT)
{
    constexpr int S0 = 144, S1 = S0 + 512, S2 = S1 + 13312;
    constexpr int S3 = S2 + 51200, S4 = S3 + 53248, S5 = S4 + 190464;
    const int idx = blockIdx.x * 256 + threadIdx.x;
    if (idx < S0) {
        const int t = idx;
        if (t < 32) {
            const float sc = g2[t] / sqrtf(v2[t] + EPS);
            scsh[t] = sc; scsh[32 + t] = (b2[t] - m2[t]) * sc + be2[t];
        } else if (t < 96) {
            const int c = t - 32;
            const float sc = g3[c] / sqrtf(v3[c] + EPS);
            scsh[64 + c] = sc; scsh[128 + c] = (b3[c] - m3[c]) * sc + be3[c];
        } else if (t < 128) {
            const int c = t - 96;
            const float sc = g4[c] / sqrtf(v4[c] + EPS);
            scsh[192 + c] = sc; scsh[224 + c] = (b4[c] - m4[c]) * sc + be4[c];
        } else {
            const int c = t - 128;
            const float sc = g1[c] / sqrtf(v1[c] + EPS);
            scsh[256 + c] = sc; scsh[272 + c] = (b1[c] - m1[c]) * sc + be1[c];
        }
    } else if (idx < S1) {
        const int i = idx - S0;
        const int j = i & 7, lane = i >> 3;
        const int k = ((lane >> 4) & 3) * 8 + j;
        A1[i] = f2bf((k < 25) ? w1[(lane & 15) * 25 + k] : 0.f);
    } else if (idx < S2) {
        packA(w2, A2, idx - S1, 16, 2);
    } else if (idx < S3) {
        packA(w3, A3, idx - S2, 32, 4);
    } else if (idx < S4) {
        const int i = idx - S3;
        const int j = i & 7, lane = (i >> 3) & 63, pc = i >> 9;  // pc = p*2+ct
        const int p = pc >> 1, ct = pc & 1;
        const int g = lane >> 4;
        const int tp = p % 13, qt = p / 13;
        const int tap = tp * 2 + (g >> 1);
        const int ci = qt * 16 + (g & 1) * 8 + j;
        const int co = ct * 16 + (lane & 15);
        A4[i] = f2bf((tap < 25) ? w4[((size_t)co * 64 + ci) * 25 + tap] : 0.f);
    } else if (idx < S5) {
        const int i = idx - S4;
        const int o = i / 5952, j = i % 5952;
        const int c = j & 31, yx = j >> 5;
        wfcT[i] = f2bf(wfc[(size_t)o * 5952 + c * 186 + yx]);
    }
}

// ---------------------------------------------------------------------------
// Stage 1 via MFMA: x [8,1,100,7500] -> c1o bf16 [120][50][250][16].
// ---------------------------------------------------------------------------
__global__ __launch_bounds__(256) void conv1_mfma(
    const float* __restrict__ x,
    const unsigned short* __restrict__ Apk1,
    const float* __restrict__ sc, const float* __restrict__ sh,
    unsigned short* __restrict__ out)
{
    constexpr int RSTR = 70;
    __shared__ unsigned short tile[12 * RSTR];
    const int n = blockIdx.z;
    const int y0 = blockIdx.y * 8, x0 = blockIdx.x * 64;
    const int b = n / 15, c = n % 15;
    const float* xb = x + (size_t)b * 100 * 7500 + (size_t)c * 500;
    const int tid = threadIdx.x;

    for (int i = tid; i < 12 * 68; i += 256) {
        const int yy = i / 68, xx = i % 68;
        const int gy = y0 - 2 + yy, gx = x0 - 2 + xx;
        float v = 0.f;
        if (gy >= 0 && gy < 100 && gx >= 0 && gx < 500) v = xb[gy * 7500 + gx];
        tile[yy * RSTR + xx] = f2bf(v);
    }

    const int lane = tid & 63, wav = tid >> 6;
    const int g = lane >> 4, c15 = lane & 15;
    const bf16x8 a = *(const bf16x8*)(Apk1 + lane * 8);

    int off[8];
    #pragma unroll
    for (int j = 0; j < 8; ++j) {
        int tap = g * 8 + j;
        if (tap > 24) tap = 24;
        off[j] = (tap / 5) * RSTR + (tap % 5);
    }
    __syncthreads();

    f32x4 acc[2][4] = {};
    #pragma unroll
    for (int r = 0; r < 2; ++r)
        #pragma unroll
        for (int cg = 0; cg < 4; ++cg) {
            const int base = (2 * wav + r) * RSTR + cg * 16 + c15;
            bf16x8 bfrag;
            #pragma unroll
            for (int j = 0; j < 8; ++j)
                ((unsigned short*)&bfrag)[j] = (short)tile[base + off[j]];
            acc[r][cg] = __builtin_amdgcn_mfma_f32_16x16x32_bf16(a, bfrag, acc[r][cg], 0, 0, 0);
        }

    const int py = blockIdx.y * 4 + wav;
    const float4 scv = *(const float4*)(sc + g * 4);
    const float4 shv = *(const float4*)(sh + g * 4);
    #pragma unroll
    for (int cg = 0; cg < 4; ++cg) {
        const int px = (x0 >> 1) + cg * 8 + (c15 >> 1);
        ushort4 st;
        #pragma unroll
        for (int reg = 0; reg < 4; ++reg) {
            const float scr = (&scv.x)[reg], shr = (&shv.x)[reg];
            const float v0 = fmaxf(acc[0][cg][reg] * scr + shr, 0.f);
            const float v1 = fmaxf(acc[1][cg][reg] * scr + shr, 0.f);
            float mx = fmaxf(v0, v1);
            mx = fmaxf(mx, __shfl_xor(mx, 1));
            (&st.x)[reg] = f2bf(mx);
        }
        if ((lane & 1) == 0 && py < 50 && px < 250)
            *(ushort4*)(out + (((size_t)n * 50 + py) * 250 + px) * 16 + g * 4) = st;
    }
}

// ---------------------------------------------------------------------------
// MFMA conv stages 2-3: channel-plane LDS, templated tile width TWP.
// ---------------------------------------------------------------------------
template <int CI, int CO, int H, int W, int PH, int PW, int NP, int NCT, int TWP>
__global__ __launch_bounds__(256) void mfma_conv(
    const unsigned short* __restrict__ in,
    const unsigned short* __restrict__ Apk,
    const float* __restrict__ sc, const float* __restrict__ sh,
    unsigned short* __restrict__ outp)
{
    constexpr int TH = 8, COLS = TWP + 4, ROWS = TH + 4, NCG = TWP / 16;
    constexpr int CPC = CI / 8;
    constexpr int PLANESZ = ROWS * COLS * 16;
    constexpr int PPAD = (CPC == 2) ? 64 : (CPC == 4 ? 32 : 16);
    constexpr int PSTR = PLANESZ + PPAD;
    constexpr int COTALL = CO / 16;
    constexpr int COB = CO / (16 * NCT);
    __shared__ char smem[CPC * PSTR];

    const int n = blockIdx.z / COB, cob = blockIdx.z % COB;
    const int ytile = blockIdx.y * TH, xtile = blockIdx.x * TWP;
    const int tid = threadIdx.x;

    for (int i = tid; i < ROWS * COLS * CPC; i += 256) {
        const int cell = i / CPC, ch = i % CPC;
        const int yy = cell / COLS, xx = cell % COLS;
        const int gy = ytile - 2 + yy, gx = xtile - 2 + xx;
        uint4 val = make_uint4(0, 0, 0, 0);
        if (gy >= 0 && gy < H && gx >= 0 && gx < W)
            val = *(const uint4*)(in + ((((size_t)n * H + gy) * W + gx) * CI + ch * 8));
        *(uint4*)(smem + ch * PSTR + cell * 16) = val;
    }
    __syncthreads();

    const int lane = tid & 63, wav = tid >> 6;
    const int g = lane >> 4, c15 = lane & 15;
    const bool hi = (lane >= 32);
    const int plane = (CI == 16) ? (g & 1) : g;
    const char* bbase = smem + plane * PSTR + ((wav * 2) * COLS + c15) * 16;

    f32x4 acc[2][NCT][NCG] = {};

    #pragma unroll
    for (int p = 0; p < NP; ++p) {
        int Dv = 0;
        if (CI == 16) {
            int t0 = p * 2;     if (t0 > 24) t0 = 24;
            int t1 = p * 2 + 1; if (t1 > 24) t1 = 24;
            const int D0 = ((t0 / 5) * COLS + t0 % 5) * 16;
            const int D1 = ((t1 / 5) * COLS + t1 % 5) * 16;
            Dv = hi ? D1 : D0;
        }
        const int tap = (CI == 32) ? p : ((CI == 64) ? (p >> 1) : 0);
        const int pimm = (CI == 64) ? (p & 1) * 4 * PSTR : 0;

        bf16x8 a[NCT], b[2][NCG];
        #pragma unroll
        for (int ct = 0; ct < NCT; ++ct)
            a[ct] = *(const bf16x8*)(Apk +
                ((size_t)(p * COTALL + cob * NCT + ct) * 64 + lane) * 8);
        #pragma unroll
        for (int r = 0; r < 2; ++r)
            #pragma unroll
            for (int cg = 0; cg < NCG; ++cg) {
                const int imm = (CI == 16)
                    ? (r * COLS + cg * 16) * 16
                    : (((r + tap / 5) * COLS + cg * 16 + tap % 5) * 16 + pimm);
                b[r][cg] = *(const bf16x8*)(bbase + Dv + imm);
            }
        #pragma unroll
        for (int r = 0; r < 2; ++r)
            #pragma unroll
            for (int ct = 0; ct < NCT; ++ct)
                #pragma unroll
                for (int cg = 0; cg < NCG; ++cg)
                    acc[r][ct][cg] = __builtin_amdgcn_mfma_f32_16x16x32_bf16(
                        a[ct], b[r][cg], acc[r][ct][cg], 0, 0, 0);
    }

    const int py = blockIdx.y * 4 + wav;
    #pragma unroll
    for (int ct = 0; ct < NCT; ++ct) {
        const int coW = (cob * NCT + ct) * 16;
        const float4 scv = *(const float4*)(sc + coW + g * 4);
        const float4 shv = *(const float4*)(sh + coW + g * 4);
        #pragma unroll
        for (int cg = 0; cg < NCG; ++cg) {
            const int px = (xtile >> 1) + cg * 8 + (c15 >> 1);
            ushort4 st;
            #pragma unroll
            for (int reg = 0; reg < 4; ++reg) {
                const float scr = (&scv.x)[reg], shr = (&shv.x)[reg];
                const float v0 = fmaxf(acc[0][ct][cg][reg] * scr + shr, 0.f);
                const float v1 = fmaxf(acc[1][ct][cg][reg] * scr + shr, 0.f);
                float mx = fmaxf(v0, v1);
                mx = fmaxf(mx, __shfl_xor(mx, 1));
                (&st.x)[reg] = f2bf(mx);
            }
            if ((lane & 1) == 0 && py < PH && px < PW)
                *(ushort4*)(outp + (((size_t)n * PH + py) * PW + px) * CO + coW + g * 4) = st;
        }
    }
}

// ---------------------------------------------------------------------------
// Fused stage4 + FC: one block per n (512 thr, 8 waves).
// c3o [12][62][64] staged in 4 ci-quarters (2 planes of [16][66] cells);
// A4 pair-packed (2 taps x 16 ci per MFMA, hi-group selects tap).
// Waves 0-5 each own pooled row py=wav. feats -> LDS -> FC -> res[n][32].
// ---------------------------------------------------------------------------
__global__ __launch_bounds__(512) void conv4fc_kernel(
    const unsigned short* __restrict__ in,
    const unsigned short* __restrict__ Apk,
    const float* __restrict__ sc, const float* __restrict__ sh,
    const unsigned short* __restrict__ wfcT,
    const float* __restrict__ bfc, float* __restrict__ res)
{
    constexpr int COLS = 66, ROWS = 16;
    constexpr int PLANESZ = ROWS * COLS * 16;      // 16896
    constexpr int PSTR = PLANESZ + 32;             // 16928
    __shared__ char smem[2 * PSTR + 6 * 31 * 32 * 2];   // 45760 B
    unsigned short* feats = (unsigned short*)(smem + 2 * PSTR);

    const int n = blockIdx.x;
    const int tid = threadIdx.x;
    const int lane = tid & 63, wav = tid >> 6;
    const int g = lane >> 4, c15 = lane & 15;
    const bool hi = (lane >= 32);

    const char* bbase = smem + (g & 1) * PSTR + ((wav * 2) * COLS + c15) * 16;
    f32x4 acc[2][2][4] = {};                       // [r][ct][cg]

    for (int qt = 0; qt < 4; ++qt) {
        __syncthreads();                           // protect prior-quarter reads
        for (int i = tid; i < ROWS * COLS * 2; i += 512) {
            const int pl = i & 1, cell = i >> 1;
            const int row = cell / COLS, col = cell - row * COLS;
            const int gy = row - 2, gx = col - 2;
            uint4 val = make_uint4(0, 0, 0, 0);
            if (gy >= 0 && gy < 12 && gx >= 0 && gx < 62)
                val = *(const uint4*)(in +
                    ((((size_t)n * 12 + gy) * 62 + gx) * 64 + qt * 16 + pl * 8));
            *(uint4*)(smem + pl * PSTR + cell * 16) = val;
        }
        __syncthreads();
        if (wav < 6) {
            #pragma unroll
            for (int tp = 0; tp < 13; ++tp) {
                const int p = qt * 13 + tp;
                int t0 = tp * 2;     if (t0 > 24) t0 = 24;
                int t1 = tp * 2 + 1; if (t1 > 24) t1 = 24;
                const int D0 = ((t0 / 5) * COLS + t0 % 5) * 16;
                const int D1 = ((t1 / 5) * COLS + t1 % 5) * 16;
                const int Dv = hi ? D1 : D0;
                bf16x8 a[2], b[2][4];
                #pragma unroll
                for (int ct = 0; ct < 2; ++ct)
                    a[ct] = *(const bf16x8*)(Apk + ((size_t)(p * 2 + ct) * 64 + lane) * 8);
                #pragma unroll
                for (int r = 0; r < 2; ++r)
                    #pragma unroll
                    for (int cg = 0; cg < 4; ++cg)
                        b[r][cg] = *(const bf16x8*)(bbase + Dv + (r * COLS + cg * 16) * 16);
                #pragma unroll
                for (int r = 0; r < 2; ++r)
                    #pragma unroll
                    for (int ct = 0; ct < 2; ++ct)
                        #pragma unroll
                        for (int cg = 0; cg < 4; ++cg)
                            acc[r][ct][cg] = __builtin_amdgcn_mfma_f32_16x16x32_bf16(
                                a[ct], b[r][cg], acc[r][ct][cg], 0, 0, 0);
            }
        }
    }

    // epilogue: BN + ReLU + pool2x2 -> feats LDS [6][31][32]
    if (wav < 6) {
        const int py = wav;
        #pragma unroll
        for (int ct = 0; ct < 2; ++ct) {
            const int coW = ct * 16;
            const float4 scv = *(const float4*)(sc + coW + g * 4);
            const float4 shv = *(const float4*)(sh + coW + g * 4);
            #pragma unroll
            for (int cg = 0; cg < 4; ++cg) {
                const int px = cg * 8 + (c15 >> 1);
                ushort4 st;
                #pragma unroll
                for (int reg = 0; reg < 4; ++reg) {
                    const float scr = (&scv.x)[reg], shr = (&shv.x)[reg];
                    const float v0 = fmaxf(acc[0][ct][cg][reg] * scr + shr, 0.f);
                    const float v1 = fmaxf(acc[1][ct][cg][reg] * scr + shr, 0.f);
                    float mx = fmaxf(v0, v1);
                    mx = fmaxf(mx, __shfl_xor(mx, 1));
                    (&st.x)[reg] = f2bf(mx);
                }
                if ((lane & 1) == 0 && px < 31)
                    *(ushort4*)(feats + (py * 31 + px) * 32 + coW + g * 4) = st;
            }
        }
    }
    __syncthreads();

    // FC: 8 waves x 4 outputs; feats LDS . wfcT global
    #pragma unroll
    for (int oi = 0; oi < 4; ++oi) {
        const int o = wav * 4 + oi;
        const unsigned short* wr = wfcT + (size_t)o * 5952;
        float s = 0.f;
        #pragma unroll
        for (int ii = 0; ii < 12; ++ii) {
            const int j8 = (ii * 64 + lane) * 8;
            if (j8 < 5952) {
                const bf16x8 fv = *(const bf16x8*)(feats + j8);
                const bf16x8 wv = *(const bf16x8*)(wr + j8);
                #pragma unroll
                for (int q = 0; q < 8; ++q)
                    s += bf2f(((const unsigned short*)&fv)[q]) *
                         bf2f(((const unsigned short*)&wv)[q]);
            }
        }
        #pragma unroll
        for (int off = 32; off > 0; off >>= 1) s += __shfl_down(s, off, 64);
        if (lane == 0) res[n * 32 + o] = s + bfc[o];
    }
}

// ---------------------------------------------------------------------------
// DPCNN head, one block of 512. res f32 [120,32] -> out [8,2]
// ---------------------------------------------------------------------------
__global__ __launch_bounds__(512) void dpcnn_kernel(
    const float* __restrict__ res,
    const float* __restrict__ wc3, const float* __restrict__ bc3,
    const float* __restrict__ wout, const float* __restrict__ bout,
    float* __restrict__ out)
{
    __shared__ float rr[8][15][32];
    __shared__ float ar[8][15][34];
    __shared__ float tr[8][15][34];
    __shared__ float px[8][15][16];
    __shared__ float wk[15][45];
    __shared__ float bk[15];

    const int tid = threadIdx.x;
    for (int i = tid; i < 15 * 45; i += 512) ((float*)wk)[i] = wc3[i];
    if (tid < 15) bk[tid] = bc3[tid];
    for (int i = tid; i < 8 * 15 * 32; i += 512) {
        const int h = i & 31, c = (i >> 5) % 15, b = i / 480;
        const float val = res[i];
        rr[b][c][h] = val;
        ar[b][c][h + 1] = fmaxf(val, 0.f);
    }
    for (int i = tid; i < 8 * 15; i += 512) {
        const int c = i % 15, b = i / 15;
        ar[b][c][0] = 0.f; ar[b][c][33] = 0.f;
        tr[b][c][0] = 0.f; tr[b][c][33] = 0.f;
    }
    __syncthreads();

    #define CONV45(SRC, BCH, CCH, HH)                                          \
        float s0 = bk[CCH], s1 = 0.f, s2 = 0.f;                                \
        {                                                                      \
            const float* srow = &SRC[BCH][0][HH];                              \
            const float* wrow = &wk[CCH][0];                                   \
            _Pragma("unroll")                                                  \
            for (int ci = 0; ci < 15; ++ci) {                                  \
                s0 += wrow[ci * 3 + 0] * srow[ci * 34 + 0];                    \
                s1 += wrow[ci * 3 + 1] * srow[ci * 34 + 1];                    \
                s2 += wrow[ci * 3 + 2] * srow[ci * 34 + 2];                    \
            }                                                                  \
        }                                                                      \
        const float val = s0 + s1 + s2;

    {
        for (int i = tid; i < 8 * 15 * 32; i += 512) {
            const int h = i & 31, cc = (i >> 5) % 15, b = i / 480;
            CONV45(ar, b, cc, h)
            tr[b][cc][h + 1] = fmaxf(val, 0.f);
        }
        __syncthreads();
        for (int i = tid; i < 8 * 15 * 32; i += 512) {
            const int h = i & 31, cc = (i >> 5) % 15, b = i / 480;
            CONV45(tr, b, cc, h)
            rr[b][cc][h] = val;
            ar[b][cc][h + 1] = fmaxf(val, 0.f);
        }
        __syncthreads();
    }

    for (int H = 32; H > 2; H >>= 1) {
        const int Hh = H >> 1;
        const int NE = 8 * 15 * Hh;
        for (int i = tid; i < NE; i += 512) {
            const int h = i % Hh, cc = (i / Hh) % 15, b = i / (15 * Hh);
            const float m0 = rr[b][cc][2 * h], m1 = rr[b][cc][2 * h + 1];
            const float m2 = (2 * h + 2 < H) ? rr[b][cc][2 * h + 2] : 0.f;
            const float pv = fmaxf(fmaxf(m0, m1), m2);
            px[b][cc][h] = pv;
            ar[b][cc][h + 1] = fmaxf(pv, 0.f);
            if (h == 0) ar[b][cc][0] = 0.f;
            if (h == Hh - 1) ar[b][cc][Hh + 1] = 0.f;
        }
        __syncthreads();
        for (int i = tid; i < NE; i += 512) {
            const int h = i % Hh, cc = (i / Hh) % 15, b = i / (15 * Hh);
            CONV45(ar, b, cc, h)
            tr[b][cc][h + 1] = fmaxf(val, 0.f);
            if (h == 0) tr[b][cc][0] = 0.f;
            if (h == Hh - 1) tr[b][cc][Hh + 1] = 0.f;
        }
        __syncthreads();
        for (int i = tid; i < NE; i += 512) {
            const int h = i % Hh, cc = (i / Hh) % 15, b = i / (15 * Hh);
            CONV45(tr, b, cc, h)
            const float rv = val + px[b][cc][h];
            rr[b][cc][h] = rv;
            ar[b][cc][h + 1] = fmaxf(rv, 0.f);
        }
        __syncthreads();
    }
    #undef CONV45

    if (tid < 16) {
        const int b = tid >> 1, o = tid & 1;
        float s = bout[o];
        for (int c = 0; c < 15; ++c)
            #pragma unroll
            for (int h = 0; h < 2; ++h)
                s += wout[o * 30 + c * 2 + h] * rr[b][c][h];
        out[b * 2 + o] = s;
    }
}

// ---------------------------------------------------------------------------
extern "C" void kernel_launch(void* const* d_in, const int* in_sizes, int n_in,
                              void* d_out, int out_size, void* d_ws, size_t ws_size,
                              hipStream_t stream)
{
    const float* x = (const float*)d_in[0];
    const float* w1 = (const float*)d_in[1];  const float* b1 = (const float*)d_in[2];
    const float* g1 = (const float*)d_in[3];  const float* be1 = (const float*)d_in[4];
    const float* m1 = (const float*)d_in[5];  const float* v1 = (const float*)d_in[6];
    const float* w2 = (const float*)d_in[7];  const float* b2 = (const float*)d_in[8];
    const float* g2 = (const float*)d_in[9];  const float* be2 = (const float*)d_in[10];
    const float* m2 = (const float*)d_in[11]; const float* v2 = (const float*)d_in[12];
    const float* w3 = (const float*)d_in[13]; const float* b3 = (const float*)d_in[14];
    const float* g3 = (const float*)d_in[15]; const float* be3 = (const float*)d_in[16];
    const float* m3 = (const float*)d_in[17]; const float* v3 = (const float*)d_in[18];
    const float* w4 = (const float*)d_in[19]; const float* b4 = (const float*)d_in[20];
    const float* g4 = (const float*)d_in[21]; const float* be4 = (const float*)d_in[22];
    const float* m4 = (const float*)d_in[23]; const float* v4 = (const float*)d_in[24];
    const float* wfc = (const float*)d_in[25]; const float* bfc = (const float*)d_in[26];
    const float* wc3 = (const float*)d_in[27]; const float* bc3 = (const float*)d_in[28];
    const float* wout = (const float*)d_in[29]; const float* bout = (const float*)d_in[30];
    float* out = (float*)d_out;

    (void)in_sizes; (void)n_in; (void)out_size; (void)ws_size;

    // ---- workspace layout (float offsets) ----
    float* wsf = (float*)d_ws;
    float* res   = wsf;                               // [120*32]
    float* scsh  = wsf + 3840;                        // 288 floats
    float* sc2 = scsh, *sh2 = scsh + 32;
    float* sc3 = scsh + 64, *sh3 = scsh + 128;
    float* sc4 = scsh + 192, *sh4 = scsh + 224;
    float* sc1 = scsh + 256, *sh1 = scsh + 272;
    unsigned short* A1  = (unsigned short*)(wsf + 4160);      // 512 sh
    unsigned short* A2  = (unsigned short*)(wsf + 4416);      // 13312 sh
    unsigned short* A3  = (unsigned short*)(wsf + 11072);     // 51200 sh
    unsigned short* A4  = (unsigned short*)(wsf + 36672);     // 53248 sh -> 63296
    unsigned short* c1o = (unsigned short*)(wsf + 63360);     // [120][50][250][16]
    unsigned short* c2o = (unsigned short*)(wsf + 12063360);  // [120][25][125][32]
    unsigned short* c3o = (unsigned short*)(wsf + 18063360);  // [120][12][62][64]
    unsigned short* wfcT = (unsigned short*)(wsf + 20920320); // 190464 sh

    // ---- single merged prep (308880 elems -> 1207 blocks) ----
    prep_all<<<1207, 256, 0, stream>>>(
        w1, w2, w3, w4, wfc,
        g1, be1, m1, v1, b1, g2, be2, m2, v2, b2,
        g3, be3, m3, v3, b3, g4, be4, m4, v4, b4,
        scsh, A1, A2, A3, A4, wfcT);

    // ---- pipeline (6 launches) ----
    conv1_mfma<<<dim3(8, 13, 120), 256, 0, stream>>>(x, A1, sc1, sh1, c1o);
    mfma_conv<16, 32, 50, 250, 25, 125, 13, 2, 64><<<dim3(4, 7, 120), 256, 0, stream>>>(
        c1o, A2, sc2, sh2, c2o);
    mfma_conv<32, 64, 25, 125, 12, 62, 25, 4, 32><<<dim3(4, 3, 120), 256, 0, stream>>>(
        c2o, A3, sc3, sh3, c3o);
    conv4fc_kernel<<<dim3(120), 512, 0, stream>>>(
        c3o, A4, sc4, sh4, wfcT, bfc, res);
    dpcnn_kernel<<<dim3(1), 512, 0, stream>>>(res, wc3, bc3, wout, bout, out);
}